// Round 10
// baseline (680.340 us; speedup 1.0000x reference)
//
#include <hip/hip_runtime.h>
#include <hip/hip_bf16.h>
#include <math.h>

#define NTOK   8192   // B*T = 4*2048
#define DM     1024   // d_model
#define DH     4096   // hidden
#define NE     8      // experts
#define CAP    18432  // max gathered rows: 2*8192 + 8*255, rounded up to 256
#define NTIL   (CAP/256)   // 72 row-tiles of 256

typedef __bf16 bf16;
typedef __bf16 bf16x4 __attribute__((ext_vector_type(4)));
typedef __bf16 bf16x8 __attribute__((ext_vector_type(8)));
typedef float  f32x4  __attribute__((ext_vector_type(4)));

__device__ __forceinline__ void gload16(const void* g, void* l) {
  __builtin_amdgcn_global_load_lds(
      (const __attribute__((address_space(1))) void*)g,
      (__attribute__((address_space(3))) void*)l, 16, 0, 0);
}

// fast GELU (tanh form)
__device__ __forceinline__ float gelu_f(float v) {
  float u = v * v * v;
  float t = 1.5957691216f * v + 0.0713548162726f * u;
  float e = __expf(-t);
  return v * __builtin_amdgcn_rcpf(1.0f + e);
}

// ------------- fp32 [E][R][C] -> bf16 [E][C][R] tiled transpose -------------
__global__ void transpose_convert_kernel(const float* __restrict__ src,
                                         bf16* __restrict__ dst, int R, int C) {
  __shared__ bf16 tile[64][66];
  int e = blockIdx.z;
  src += (size_t)e * R * C;
  dst += (size_t)e * R * C;
  int c0 = blockIdx.x * 64;
  int r0 = blockIdx.y * 64;
  int lr = threadIdx.x >> 6;   // 0..3
  int lc = threadIdx.x & 63;
#pragma unroll
  for (int i = 0; i < 16; i++) {
    int r = lr + i * 4;
    tile[r][lc] = (bf16)src[(size_t)(r0 + r) * C + c0 + lc];
  }
  __syncthreads();
#pragma unroll
  for (int i = 0; i < 16; i++) {
    int r = lr + i * 4;  // row of dst block (= src col)
    dst[(size_t)(c0 + r) * R + r0 + lc] = tile[lc][r];
  }
}

// -- gating fused with x->bf16 convert: logits -> top2 -> softmax weights --
__global__ void gating_kernel(const float* __restrict__ x,
                              const float* __restrict__ gw,
                              const float* __restrict__ gb,
                              bf16* __restrict__ xb,
                              int* __restrict__ assignE,
                              float2* __restrict__ assignW) {
  int wave = threadIdx.x >> 6, lane = threadIdx.x & 63;
  int t = blockIdx.x * 4 + wave;
  const float* xr = x + (size_t)t * DM;
  // each lane owns 16 contiguous d: [lane*16, lane*16+16)
  float4 xv[4];
  const float4* xr4 = reinterpret_cast<const float4*>(xr) + lane * 4;
#pragma unroll
  for (int i = 0; i < 4; i++) xv[i] = xr4[i];
  // convert + store bf16 x
#pragma unroll
  for (int i = 0; i < 2; i++) {
    float4 a = xv[2 * i], b = xv[2 * i + 1];
    bf16x8 o;
    o[0] = (bf16)a.x; o[1] = (bf16)a.y; o[2] = (bf16)a.z; o[3] = (bf16)a.w;
    o[4] = (bf16)b.x; o[5] = (bf16)b.y; o[6] = (bf16)b.z; o[7] = (bf16)b.w;
    reinterpret_cast<bf16x8*>(xb + (size_t)t * DM)[lane * 2 + i] = o;
  }
  // gate logits
  float acc[8];
#pragma unroll
  for (int e = 0; e < 8; e++) acc[e] = 0.f;
  int d0 = lane * 16;
#pragma unroll
  for (int j = 0; j < 16; j++) {
    float xvj = reinterpret_cast<const float*>(xv)[j];
    const float4* g = reinterpret_cast<const float4*>(gw + (size_t)(d0 + j) * 8);
    float4 g0 = g[0], g1 = g[1];
    acc[0] += xvj * g0.x; acc[1] += xvj * g0.y; acc[2] += xvj * g0.z; acc[3] += xvj * g0.w;
    acc[4] += xvj * g1.x; acc[5] += xvj * g1.y; acc[6] += xvj * g1.z; acc[7] += xvj * g1.w;
  }
#pragma unroll
  for (int off = 32; off > 0; off >>= 1)
#pragma unroll
    for (int e = 0; e < 8; e++) acc[e] += __shfl_xor(acc[e], off, 64);
  if (lane == 0) {
    float v[8];
#pragma unroll
    for (int e = 0; e < 8; e++) v[e] = acc[e] + gb[e];
    int i0 = 0; float v0 = v[0];
#pragma unroll
    for (int e = 1; e < 8; e++) if (v[e] > v0) { v0 = v[e]; i0 = e; }
    int i1 = -1; float v1 = -1e30f;
#pragma unroll
    for (int e = 0; e < 8; e++) if (e != i0 && v[e] > v1) { v1 = v[e]; i1 = e; }
    float p1 = expf(v1 - v0);
    float den = 1.f + p1;
    assignE[t] = i0 | (i1 << 8);
    assignW[t] = make_float2(1.f / den, p1 / den);
  }
}

// ---- router (single block, 512 thr): histogram -> 256-aligned offsets ----
__global__ void router_kernel(const int* __restrict__ assignE,
                              const float2* __restrict__ assignW,
                              int* __restrict__ rowTok,
                              float* __restrict__ rowW,
                              int2* __restrict__ tokRow,
                              int* __restrict__ tileExpert) {
  __shared__ int cnt[NE], off[NE + 1], cur[NE];
  int tid = threadIdx.x;
  if (tid < NE) cnt[tid] = 0;
  __syncthreads();
  for (int t = tid; t < NTOK; t += 512) {
    int ae = assignE[t];
    atomicAdd(&cnt[ae & 255], 1);
    atomicAdd(&cnt[(ae >> 8) & 255], 1);
  }
  __syncthreads();
  if (tid == 0) {
    int o = 0;
    for (int e = 0; e < NE; e++) { off[e] = o; o += ((cnt[e] + 255) >> 8) << 8; }
    off[NE] = o;
  }
  __syncthreads();
  if (tid < NE) cur[tid] = 0;
  for (int i = tid; i < NTIL; i += 512) {
    int r = i * 256, ex = -1;
#pragma unroll
    for (int e = 0; e < NE; e++)
      if (r >= off[e] && r < off[e + 1]) ex = e;
    tileExpert[i] = ex;
  }
  for (int i = tid; i < CAP; i += 512) { rowTok[i] = -1; rowW[i] = 0.f; }
  __syncthreads();
  for (int t = tid; t < NTOK; t += 512) {
    int ae = assignE[t];
    float2 aw = assignW[t];
    int e0 = ae & 255, e1 = (ae >> 8) & 255;
    int p0 = off[e0] + atomicAdd(&cur[e0], 1);
    rowTok[p0] = t; rowW[p0] = aw.x;
    int p1 = off[e1] + atomicAdd(&cur[e1], 1);
    rowTok[p1] = t; rowW[p1] = aw.y;
    tokRow[t] = make_int2(p0, p1);
  }
}

// ---------------- grouped bf16 MFMA GEMM over expert segments ----------------
// 2-phase double-buffered K-loop (r6 verified ledger). BM=256, BN=128, BK=32,
// 8 waves (512 thr, 4Mx2N grid of 64x64 wave-tiles). LDS 48 KB -> 3 blocks/CU,
// 24 waves/CU. Swizzle for 64B rows: col16Bslot ^= (row>>1)&3 -> bank slot
// (4r + (r>>1)&3) mod 8 covers all 8 groups (2-way = free). Write side via
// pre-swizzled global source (rule #21), read side same XOR.
// EPI==0: A gathered via rowTok; Hout[r,n] = gelu(C + bias[n])  (bf16)
// EPI==1: A direct; Y[r][n] = rowW[r] * (C + bias[n])  (fp32, linear)
template <int EPI>
__global__ __launch_bounds__(512) void moe_gemm_kernel(
    const bf16* __restrict__ A, const bf16* __restrict__ Bt,
    const float* __restrict__ bias, bf16* __restrict__ Hout,
    float* __restrict__ Y,
    const int* __restrict__ rowTok, const float* __restrict__ rowW,
    const int* __restrict__ tileExpert,
    int N, int K) {
  constexpr int BM = 256, BN = 128, BK = 32;
  __shared__ __align__(16) bf16 As0[BM * BK];   // 16 KB
  __shared__ __align__(16) bf16 Bs0[BN * BK];   //  8 KB
  __shared__ __align__(16) bf16 As1[BM * BK];
  __shared__ __align__(16) bf16 Bs1[BN * BK];
  const int tid = threadIdx.x;
  const int wave = tid >> 6, lane = tid & 63;   // wave 0..7
  const int nbn = N / BN;
  const int bid = (int)blockIdx.x;
  // natural order: XCD = bid % 8 -> column-stripe B-panel L2 affinity
  const int rt = bid / nbn;
  const int e = tileExpert[rt];
  if (e < 0) return;
  const int bm0 = rt * BM;
  const int bn0 = (bid % nbn) * BN;
  const int wm = (wave >> 1) * 64;              // 0,64,128,192
  const int wn = (wave & 1) * 64;               // 0,64
  const bf16* Be = Bt + (size_t)e * N * K;
  const float* be = bias + (size_t)e * N;

  f32x4 acc[4][4];
#pragma unroll
  for (int m = 0; m < 4; m++)
#pragma unroll
    for (int n = 0; n < 4; n++)
#pragma unroll
      for (int j = 0; j < 4; j++) acc[m][n][j] = 0.f;

  // staging geometry (BK=32, 64B rows): one wave-gload covers 16 rows.
  const int srow = lane >> 2;            // 0..15 within a 16-row chunk
  const int scolb = (lane & 3) << 4;     // byte slot 0..48

  // hoist per-thread row base pointers (rows fixed across K-loop)
  // A: 16 chunks -> 2 per wave; B: 8 chunks -> 1 per wave.
  const char* gaBase[2];
  const char* gbBase;
#pragma unroll
  for (int it = 0; it < 2; it++) {
    int chunk = wave * 2 + it;
    int row = chunk * 16 + srow;
    int csw = scolb ^ (((row >> 1) & 3) << 4);  // pre-swizzled source
    size_t arow;
    if constexpr (EPI == 0) {
      int tok = rowTok[bm0 + row];
      arow = (size_t)(tok < 0 ? 0 : tok);
    } else {
      arow = (size_t)(bm0 + row);
    }
    gaBase[it] = (const char*)A + arow * (size_t)K * 2 + csw;
  }
  {
    int row = wave * 16 + srow;
    int csw = scolb ^ (((row >> 1) & 3) << 4);
    gbBase = (const char*)Be + ((size_t)(bn0 + row)) * K * 2 + csw;
  }

  auto STAGE = [&](int kt, bf16* dstA, bf16* dstB) {
#pragma unroll
    for (int it = 0; it < 2; it++)
      gload16(gaBase[it] + (size_t)kt * 2, (char*)dstA + (wave * 2 + it) * 1024);
    gload16(gbBase + (size_t)kt * 2, (char*)dstB + wave * 1024);
  };

  auto COMPUTE = [&](const bf16* sA, const bf16* sB) {
    const int kb = (lane >> 4) << 4;     // 16B k-slot within 64B row
    bf16x8 af[4], bfv[4];
#pragma unroll
    for (int m = 0; m < 4; m++) {
      int r = wm + m * 16 + (lane & 15);
      af[m] = *(const bf16x8*)((const char*)sA + r * 64 + (kb ^ (((r >> 1) & 3) << 4)));
    }
#pragma unroll
    for (int n = 0; n < 4; n++) {
      int r = wn + n * 16 + (lane & 15);
      bfv[n] = *(const bf16x8*)((const char*)sB + r * 64 + (kb ^ (((r >> 1) & 3) << 4)));
    }
#pragma unroll
    for (int m = 0; m < 4; m++)
#pragma unroll
      for (int n = 0; n < 4; n++)
        acc[m][n] = __builtin_amdgcn_mfma_f32_16x16x32_bf16(af[m], bfv[n], acc[m][n], 0, 0, 0);
  };

  // prologue: fill buffer 0
  STAGE(0, As0, Bs0);
  __syncthreads();                       // vmcnt(0) + barrier: buf0 ready
  // main loop: 2 K-steps per iteration, static buffer references
  for (int kt = 0; kt < K; kt += 2 * BK) {
    if (kt + BK < K) STAGE(kt + BK, As1, Bs1);   // prefetch into buf1
    COMPUTE(As0, Bs0);
    __syncthreads();                     // buf1 ready; buf0 reads done
    if (kt + 2 * BK < K) STAGE(kt + 2 * BK, As0, Bs0);  // prefetch into buf0
    COMPUTE(As1, Bs1);
    __syncthreads();                     // buf0 ready; buf1 reads done
  }

  const int rb = bm0 + wm + ((lane >> 4) << 2);
  const int cb = bn0 + wn + (lane & 15);
  if constexpr (EPI == 0) {
#pragma unroll
    for (int m = 0; m < 4; m++)
#pragma unroll
      for (int n = 0; n < 4; n++) {
        int c = cb + n * 16;
        float bv = be[c];
#pragma unroll
        for (int j = 0; j < 4; j++) {
          int r = rb + m * 16 + j;
          Hout[(size_t)r * N + c] = (bf16)gelu_f(acc[m][n][j] + bv);
        }
      }
  } else {
#pragma unroll
    for (int m = 0; m < 4; m++) {
#pragma unroll
      for (int j = 0; j < 4; j++) {
        int r = rb + m * 16 + j;
        float w = rowW[r];
        float* yrow = Y + (size_t)r * DM;
#pragma unroll
        for (int n = 0; n < 4; n++) {
          int c = cb + n * 16;
          yrow[c] = w * (acc[m][n][j] + be[c]);
        }
      }
    }
  }
}

// ---------------- combine: out[t] = Y[p0] + Y[p1] ----------------
__global__ void combine_kernel(const float* __restrict__ Y,
                               const int2* __restrict__ tokRow,
                               float* __restrict__ out) {
  int wave = threadIdx.x >> 6, lane = threadIdx.x & 63;
  int t = blockIdx.x * 4 + wave;
  int2 pr = tokRow[t];
  const float4* a = (const float4*)(Y + (size_t)pr.x * DM);
  const float4* b = (const float4*)(Y + (size_t)pr.y * DM);
  float4* o = (float4*)(out + (size_t)t * DM);
#pragma unroll
  for (int i = 0; i < 4; i++) {
    int idx = lane + i * 64;
    float4 u = a[idx], v = b[idx];
    o[idx] = make_float4(u.x + v.x, u.y + v.y, u.z + v.z, u.w + v.w);
  }
}

extern "C" void kernel_launch(void* const* d_in, const int* in_sizes, int n_in,
                              void* d_out, int out_size, void* d_ws, size_t ws_size,
                              hipStream_t stream) {
  const float* x  = (const float*)d_in[0];
  const float* gw = (const float*)d_in[1];
  const float* gb = (const float*)d_in[2];
  const float* w1 = (const float*)d_in[3];
  const float* b1 = (const float*)d_in[4];
  const float* w2 = (const float*)d_in[5];
  const float* b2 = (const float*)d_in[6];
  float* out = (float*)d_out;

  char* p = (char*)d_ws;
  bf16* xb   = (bf16*)p;  p += (size_t)NTOK * DM * 2;      // 16.8 MB (dead after GEMM1)
  bf16* w1t  = (bf16*)p;  p += (size_t)NE * DM * DH * 2;   // 67 MB   (dead after GEMM1)
  bf16* Hg   = (bf16*)p;  p += (size_t)CAP * DH * 2;       // 151 MB
  bf16* w2t  = (bf16*)p;  p += (size_t)NE * DM * DH * 2;   // 67 MB  [E][D][H]
  int*   assignE = (int*)p;     p += (size_t)NTOK * 4;
  float2* assignW = (float2*)p; p += (size_t)NTOK * 8;
  int*   rowTok = (int*)p;      p += (size_t)CAP * 4;
  float* rowW   = (float*)p;    p += (size_t)CAP * 4;
  int2*  tokRow = (int2*)p;     p += (size_t)NTOK * 8;
  int*   tileExpert = (int*)p;  p += (size_t)NTIL * 4;
  // Y aliases xb+w1t (75.5 MB <= 83.9 MB; both dead once GEMM2 runs)
  float* Y = (float*)d_ws;

  // w1 [E][DM][DH] -> w1t [E][DH][DM]
  transpose_convert_kernel<<<dim3(DH / 64, DM / 64, NE), 256, 0, stream>>>(w1, w1t, DM, DH);
  // w2 [E][DH][DM] -> w2t [E][DM][DH]
  transpose_convert_kernel<<<dim3(DM / 64, DH / 64, NE), 256, 0, stream>>>(w2, w2t, DH, DM);
  gating_kernel<<<NTOK / 4, 256, 0, stream>>>(x, gw, gb, xb, assignE, assignW);
  router_kernel<<<1, 512, 0, stream>>>(assignE, assignW, rowTok, rowW, tokRow, tileExpert);

  // GEMM1: gathered x @ w1^T -> gelu -> Hg   [CAP x DH]
  moe_gemm_kernel<0><<<NTIL * (DH / 128), 512, 0, stream>>>(
      xb, w1t, b1, Hg, nullptr, rowTok, nullptr, tileExpert, DH, DM);
  // GEMM2: Hg @ w2^T -> Y[r] = w*(y+b2)  (linear, gathered-row space)
  moe_gemm_kernel<1><<<NTIL * (DM / 128), 512, 0, stream>>>(
      Hg, w2t, b2, nullptr, Y, rowTok, rowW, tileExpert, DM, DH);

  combine_kernel<<<NTOK / 4, 256, 0, stream>>>(Y, tokRow, out);
}

// Round 11
// 607.025 us; speedup vs baseline: 1.1208x; 1.1208x over previous
//
#include <hip/hip_runtime.h>
#include <hip/hip_bf16.h>
#include <math.h>

#define NTOK   8192   // B*T = 4*2048
#define DM     1024   // d_model
#define DH     4096   // hidden
#define NE     8      // experts
#define CAP    17408  // max gathered rows: 2*NTOK + 8*127, rounded up to 128
#define CAPT   (CAP/128)   // 136 row-tiles

typedef __bf16 bf16;
typedef __bf16 bf16x4 __attribute__((ext_vector_type(4)));
typedef __bf16 bf16x8 __attribute__((ext_vector_type(8)));
typedef float  f32x4  __attribute__((ext_vector_type(4)));

__device__ __forceinline__ void gload16(const void* g, void* l) {
  __builtin_amdgcn_global_load_lds(
      (const __attribute__((address_space(1))) void*)g,
      (__attribute__((address_space(3))) void*)l, 16, 0, 0);
}

// fast GELU (tanh form)
__device__ __forceinline__ float gelu_f(float v) {
  float u = v * v * v;
  float t = 1.5957691216f * v + 0.0713548162726f * u;
  float e = __expf(-t);
  return v * __builtin_amdgcn_rcpf(1.0f + e);
}

// ------------- fp32 [E][R][C] -> bf16 [E][C][R] tiled transpose -------------
__global__ void transpose_convert_kernel(const float* __restrict__ src,
                                         bf16* __restrict__ dst, int R, int C) {
  __shared__ bf16 tile[64][66];
  int e = blockIdx.z;
  src += (size_t)e * R * C;
  dst += (size_t)e * R * C;
  int c0 = blockIdx.x * 64;
  int r0 = blockIdx.y * 64;
  int lr = threadIdx.x >> 6;   // 0..3
  int lc = threadIdx.x & 63;
#pragma unroll
  for (int i = 0; i < 16; i++) {
    int r = lr + i * 4;
    tile[r][lc] = (bf16)src[(size_t)(r0 + r) * C + c0 + lc];
  }
  __syncthreads();
#pragma unroll
  for (int i = 0; i < 16; i++) {
    int r = lr + i * 4;  // row of dst block (= src col)
    dst[(size_t)(c0 + r) * R + r0 + lc] = tile[lc][r];
  }
}

// -- gating fused with x->bf16 convert: logits -> top2 -> softmax weights --
__global__ void gating_kernel(const float* __restrict__ x,
                              const float* __restrict__ gw,
                              const float* __restrict__ gb,
                              bf16* __restrict__ xb,
                              int* __restrict__ assignE,
                              float2* __restrict__ assignW) {
  int wave = threadIdx.x >> 6, lane = threadIdx.x & 63;
  int t = blockIdx.x * 4 + wave;
  const float* xr = x + (size_t)t * DM;
  // each lane owns 16 contiguous d: [lane*16, lane*16+16)
  float4 xv[4];
  const float4* xr4 = reinterpret_cast<const float4*>(xr) + lane * 4;
#pragma unroll
  for (int i = 0; i < 4; i++) xv[i] = xr4[i];
  // convert + store bf16 x
#pragma unroll
  for (int i = 0; i < 2; i++) {
    float4 a = xv[2 * i], b = xv[2 * i + 1];
    bf16x8 o;
    o[0] = (bf16)a.x; o[1] = (bf16)a.y; o[2] = (bf16)a.z; o[3] = (bf16)a.w;
    o[4] = (bf16)b.x; o[5] = (bf16)b.y; o[6] = (bf16)b.z; o[7] = (bf16)b.w;
    reinterpret_cast<bf16x8*>(xb + (size_t)t * DM)[lane * 2 + i] = o;
  }
  // gate logits
  float acc[8];
#pragma unroll
  for (int e = 0; e < 8; e++) acc[e] = 0.f;
  int d0 = lane * 16;
#pragma unroll
  for (int j = 0; j < 16; j++) {
    float xvj = reinterpret_cast<const float*>(xv)[j];
    const float4* g = reinterpret_cast<const float4*>(gw + (size_t)(d0 + j) * 8);
    float4 g0 = g[0], g1 = g[1];
    acc[0] += xvj * g0.x; acc[1] += xvj * g0.y; acc[2] += xvj * g0.z; acc[3] += xvj * g0.w;
    acc[4] += xvj * g1.x; acc[5] += xvj * g1.y; acc[6] += xvj * g1.z; acc[7] += xvj * g1.w;
  }
#pragma unroll
  for (int off = 32; off > 0; off >>= 1)
#pragma unroll
    for (int e = 0; e < 8; e++) acc[e] += __shfl_xor(acc[e], off, 64);
  if (lane == 0) {
    float v[8];
#pragma unroll
    for (int e = 0; e < 8; e++) v[e] = acc[e] + gb[e];
    int i0 = 0; float v0 = v[0];
#pragma unroll
    for (int e = 1; e < 8; e++) if (v[e] > v0) { v0 = v[e]; i0 = e; }
    int i1 = -1; float v1 = -1e30f;
#pragma unroll
    for (int e = 0; e < 8; e++) if (e != i0 && v[e] > v1) { v1 = v[e]; i1 = e; }
    float p1 = expf(v1 - v0);
    float den = 1.f + p1;
    assignE[t] = i0 | (i1 << 8);
    assignW[t] = make_float2(1.f / den, p1 / den);
  }
}

// ---- router (single block, 512 thr): histogram -> offsets -> LUT -> scatter ----
__global__ void router_kernel(const int* __restrict__ assignE,
                              const float2* __restrict__ assignW,
                              int* __restrict__ rowTok,
                              float* __restrict__ rowW,
                              int2* __restrict__ tokRow,
                              int* __restrict__ tileExpert) {
  __shared__ int cnt[NE], off[NE + 1], cur[NE];
  int tid = threadIdx.x;
  if (tid < NE) cnt[tid] = 0;
  __syncthreads();
  for (int t = tid; t < NTOK; t += 512) {
    int ae = assignE[t];
    atomicAdd(&cnt[ae & 255], 1);
    atomicAdd(&cnt[(ae >> 8) & 255], 1);
  }
  __syncthreads();
  if (tid == 0) {
    int o = 0;
    for (int e = 0; e < NE; e++) { off[e] = o; o += ((cnt[e] + 127) >> 7) << 7; }
    off[NE] = o;
  }
  __syncthreads();
  if (tid < NE) cur[tid] = 0;
  for (int i = tid; i < CAPT; i += 512) {
    int r = i * 128, ex = -1;
#pragma unroll
    for (int e = 0; e < NE; e++)
      if (r >= off[e] && r < off[e + 1]) ex = e;
    tileExpert[i] = ex;
  }
  for (int i = tid; i < CAP; i += 512) { rowTok[i] = -1; rowW[i] = 0.f; }
  __syncthreads();
  for (int t = tid; t < NTOK; t += 512) {
    int ae = assignE[t];
    float2 aw = assignW[t];
    int e0 = ae & 255, e1 = (ae >> 8) & 255;
    int p0 = off[e0] + atomicAdd(&cur[e0], 1);
    rowTok[p0] = t; rowW[p0] = aw.x;
    int p1 = off[e1] + atomicAdd(&cur[e1], 1);
    rowTok[p1] = t; rowW[p1] = aw.y;
    tokRow[t] = make_int2(p0, p1);
  }
}

// ---------------- grouped bf16 MFMA GEMM over expert segments ----------------
// 2-phase double-buffered K-loop (r6-verified ledger), BM=BN=128 (r9-verified
// geometry), BK=32 (LDS 32 KB -> 4 blocks/CU, 16 waves/CU), r10-verified
// swizzle: 16B-slot ^= (row>>1)&3 -> bank slot (4r + (r>>1)&3) mod 8 covers
// all 8 groups, 2 lanes/slot = conflict-free (r10 PMC: 1.73e7 -> 0).
// Write side via pre-swizzled global source (rule #21), read side same XOR.
// EPI==0: A gathered via rowTok; Hout[r,n] = gelu(C + bias[n])  (bf16)
// EPI==1: A direct; Y[r][n] = rowW[r] * (C + bias[n])  (fp32, linear)
template <int EPI>
__global__ __launch_bounds__(256) void moe_gemm_kernel(
    const bf16* __restrict__ A, const bf16* __restrict__ Bt,
    const float* __restrict__ bias, bf16* __restrict__ Hout,
    float* __restrict__ Y,
    const int* __restrict__ rowTok, const float* __restrict__ rowW,
    const int* __restrict__ tileExpert,
    int N, int K) {
  constexpr int BM = 128, BN = 128, BK = 32;
  __shared__ __align__(16) bf16 As0[BM * BK];
  __shared__ __align__(16) bf16 Bs0[BN * BK];
  __shared__ __align__(16) bf16 As1[BM * BK];
  __shared__ __align__(16) bf16 Bs1[BN * BK];
  const int tid = threadIdx.x;
  const int wave = tid >> 6, lane = tid & 63;
  const int nbn = N / BN;
  const int bid = (int)blockIdx.x;
  // natural order: XCD = bid % 8 = fixed column stripe -> B-panel L2 affinity
  const int rt = bid / nbn;
  const int e = tileExpert[rt];
  if (e < 0) return;
  const int bm0 = rt * BM;
  const int bn0 = (bid % nbn) * BN;
  const int wm = (wave >> 1) * 64, wn = (wave & 1) * 64;
  const bf16* Be = Bt + (size_t)e * N * K;
  const float* be = bias + (size_t)e * N;

  f32x4 acc[4][4];
#pragma unroll
  for (int m = 0; m < 4; m++)
#pragma unroll
    for (int n = 0; n < 4; n++)
#pragma unroll
      for (int j = 0; j < 4; j++) acc[m][n][j] = 0.f;

  // staging geometry (BK=32, 64B rows): one wave-gload covers 16 rows.
  const int srow = lane >> 2;            // 0..15 within a 16-row chunk
  const int scolb = (lane & 3) << 4;     // byte slot 0..48

  // hoist per-thread row base pointers (rows fixed across K-loop)
  const char* gaBase[2];
  const char* gbBase[2];
#pragma unroll
  for (int it = 0; it < 2; it++) {
    int chunk = it * 4 + wave;
    int row = chunk * 16 + srow;
    int csw = scolb ^ (((row >> 1) & 3) << 4);  // pre-swizzled source (r10-verified)
    size_t arow;
    if constexpr (EPI == 0) {
      int tok = rowTok[bm0 + row];
      arow = (size_t)(tok < 0 ? 0 : tok);
    } else {
      arow = (size_t)(bm0 + row);
    }
    gaBase[it] = (const char*)A + arow * (size_t)K * 2 + csw;
    gbBase[it] = (const char*)Be + ((size_t)(bn0 + row)) * K * 2 + csw;
  }

  auto STAGE = [&](int kt, bf16* dstA, bf16* dstB) {
#pragma unroll
    for (int it = 0; it < 2; it++) {
      int chunk = it * 4 + wave;
      gload16(gaBase[it] + (size_t)kt * 2, (char*)dstA + chunk * 1024);
      gload16(gbBase[it] + (size_t)kt * 2, (char*)dstB + chunk * 1024);
    }
  };

  auto COMPUTE = [&](const bf16* sA, const bf16* sB) {
    const int kb = (lane >> 4) << 4;     // 16B k-slot within 64B row
    bf16x8 af[4], bfv[4];
#pragma unroll
    for (int m = 0; m < 4; m++) {
      int r = wm + m * 16 + (lane & 15);
      af[m] = *(const bf16x8*)((const char*)sA + r * 64 + (kb ^ (((r >> 1) & 3) << 4)));
    }
#pragma unroll
    for (int n = 0; n < 4; n++) {
      int r = wn + n * 16 + (lane & 15);
      bfv[n] = *(const bf16x8*)((const char*)sB + r * 64 + (kb ^ (((r >> 1) & 3) << 4)));
    }
#pragma unroll
    for (int m = 0; m < 4; m++)
#pragma unroll
      for (int n = 0; n < 4; n++)
        acc[m][n] = __builtin_amdgcn_mfma_f32_16x16x32_bf16(af[m], bfv[n], acc[m][n], 0, 0, 0);
  };

  // prologue: fill buffer 0
  STAGE(0, As0, Bs0);
  __syncthreads();                       // vmcnt(0) + barrier: buf0 ready
  // main loop: 2 K-steps per iteration, static buffer references
  for (int kt = 0; kt < K; kt += 2 * BK) {
    if (kt + BK < K) STAGE(kt + BK, As1, Bs1);   // prefetch into buf1
    COMPUTE(As0, Bs0);
    __syncthreads();                     // buf1 ready; buf0 reads done
    if (kt + 2 * BK < K) STAGE(kt + 2 * BK, As0, Bs0);  // prefetch into buf0
    COMPUTE(As1, Bs1);
    __syncthreads();                     // buf0 ready; buf1 reads done
  }

  const int rb = bm0 + wm + ((lane >> 4) << 2);
  const int cb = bn0 + wn + (lane & 15);
  if constexpr (EPI == 0) {
#pragma unroll
    for (int m = 0; m < 4; m++)
#pragma unroll
      for (int n = 0; n < 4; n++) {
        int c = cb + n * 16;
        float bv = be[c];
#pragma unroll
        for (int j = 0; j < 4; j++) {
          int r = rb + m * 16 + j;
          Hout[(size_t)r * N + c] = (bf16)gelu_f(acc[m][n][j] + bv);
        }
      }
  } else {
#pragma unroll
    for (int m = 0; m < 4; m++) {
#pragma unroll
      for (int j = 0; j < 4; j++) {
        int r = rb + m * 16 + j;
        float w = rowW[r];
        float* yrow = Y + (size_t)r * DM;
#pragma unroll
        for (int n = 0; n < 4; n++) {
          int c = cb + n * 16;
          yrow[c] = w * (acc[m][n][j] + be[c]);
        }
      }
    }
  }
}

// ---------------- combine: out[t] = Y[p0] + Y[p1] ----------------
__global__ void combine_kernel(const float* __restrict__ Y,
                               const int2* __restrict__ tokRow,
                               float* __restrict__ out) {
  int wave = threadIdx.x >> 6, lane = threadIdx.x & 63;
  int t = blockIdx.x * 4 + wave;
  int2 pr = tokRow[t];
  const float4* a = (const float4*)(Y + (size_t)pr.x * DM);
  const float4* b = (const float4*)(Y + (size_t)pr.y * DM);
  float4* o = (float4*)(out + (size_t)t * DM);
#pragma unroll
  for (int i = 0; i < 4; i++) {
    int idx = lane + i * 64;
    float4 u = a[idx], v = b[idx];
    o[idx] = make_float4(u.x + v.x, u.y + v.y, u.z + v.z, u.w + v.w);
  }
}

extern "C" void kernel_launch(void* const* d_in, const int* in_sizes, int n_in,
                              void* d_out, int out_size, void* d_ws, size_t ws_size,
                              hipStream_t stream) {
  const float* x  = (const float*)d_in[0];
  const float* gw = (const float*)d_in[1];
  const float* gb = (const float*)d_in[2];
  const float* w1 = (const float*)d_in[3];
  const float* b1 = (const float*)d_in[4];
  const float* w2 = (const float*)d_in[5];
  const float* b2 = (const float*)d_in[6];
  float* out = (float*)d_out;

  char* p = (char*)d_ws;
  bf16* xb   = (bf16*)p;  p += (size_t)NTOK * DM * 2;      // 16.8 MB (dead after GEMM1)
  bf16* w1t  = (bf16*)p;  p += (size_t)NE * DM * DH * 2;   // 67 MB   (dead after GEMM1)
  bf16* Hg   = (bf16*)p;  p += (size_t)CAP * DH * 2;       // 142.6 MB
  bf16* w2t  = (bf16*)p;  p += (size_t)NE * DM * DH * 2;   // 67 MB  [E][D][H]
  int*   assignE = (int*)p;     p += (size_t)NTOK * 4;
  float2* assignW = (float2*)p; p += (size_t)NTOK * 8;
  int*   rowTok = (int*)p;      p += (size_t)CAP * 4;
  float* rowW   = (float*)p;    p += (size_t)CAP * 4;
  int2*  tokRow = (int2*)p;     p += (size_t)NTOK * 8;
  int*   tileExpert = (int*)p;  p += (size_t)CAPT * 4;
  // Y aliases xb+w1t (71.3 MB <= 83.8 MB; both dead once GEMM2 runs)
  float* Y = (float*)d_ws;

  // w1 [E][DM][DH] -> w1t [E][DH][DM]
  transpose_convert_kernel<<<dim3(DH / 64, DM / 64, NE), 256, 0, stream>>>(w1, w1t, DM, DH);
  // w2 [E][DH][DM] -> w2t [E][DM][DH]
  transpose_convert_kernel<<<dim3(DM / 64, DH / 64, NE), 256, 0, stream>>>(w2, w2t, DH, DM);
  gating_kernel<<<NTOK / 4, 256, 0, stream>>>(x, gw, gb, xb, assignE, assignW);
  router_kernel<<<1, 512, 0, stream>>>(assignE, assignW, rowTok, rowW, tokRow, tileExpert);

  // GEMM1: gathered x @ w1^T -> gelu -> Hg   [CAP x DH]
  moe_gemm_kernel<0><<<CAPT * (DH / 128), 256, 0, stream>>>(
      xb, w1t, b1, Hg, nullptr, rowTok, nullptr, tileExpert, DH, DM);
  // GEMM2: Hg @ w2^T -> Y[r] = w*(y+b2)  (linear, gathered-row space)
  moe_gemm_kernel<1><<<CAPT * (DM / 128), 256, 0, stream>>>(
      Hg, w2t, b2, nullptr, Y, rowTok, rowW, tileExpert, DM, DH);

  combine_kernel<<<NTOK / 4, 256, 0, stream>>>(Y, tokRow, out);
}

// Round 12
// 564.969 us; speedup vs baseline: 1.2042x; 1.0744x over previous
//
#include <hip/hip_runtime.h>
#include <hip/hip_bf16.h>
#include <math.h>

#define NTOK   8192   // B*T = 4*2048
#define DM     1024   // d_model
#define DH     4096   // hidden
#define NE     8      // experts
#define CAP    17408  // max gathered rows: 2*NTOK + 8*127, rounded up to 128
#define CAPT   (CAP/128)   // 136 row-tiles

typedef __bf16 bf16;
typedef __bf16 bf16x4 __attribute__((ext_vector_type(4)));
typedef __bf16 bf16x8 __attribute__((ext_vector_type(8)));
typedef float  f32x4  __attribute__((ext_vector_type(4)));

__device__ __forceinline__ void gload16(const void* g, void* l) {
  __builtin_amdgcn_global_load_lds(
      (const __attribute__((address_space(1))) void*)g,
      (__attribute__((address_space(3))) void*)l, 16, 0, 0);
}

// fast GELU (tanh form)
__device__ __forceinline__ float gelu_f(float v) {
  float u = v * v * v;
  float t = 1.5957691216f * v + 0.0713548162726f * u;
  float e = __expf(-t);
  return v * __builtin_amdgcn_rcpf(1.0f + e);
}

// ------------- fp32 [E][R][C] -> bf16 [E][C][R] tiled transpose -------------
// Vectorized: float4 (16B) global reads, bf16x8 (16B) global writes.
__global__ void transpose_convert_kernel(const float* __restrict__ src,
                                         bf16* __restrict__ dst, int R, int C) {
  __shared__ bf16 tile[64][66];
  int e = blockIdx.z;
  src += (size_t)e * R * C;
  dst += (size_t)e * R * C;
  int c0 = blockIdx.x * 64;
  int r0 = blockIdx.y * 64;
  int tid = threadIdx.x;
  // read: 16 lanes/row x 4 floats; 16 rows/pass, 4 passes
  int rr = tid >> 4;         // 0..15
  int cc = (tid & 15) * 4;   // 0..60
#pragma unroll
  for (int i = 0; i < 4; i++) {
    int r = rr + i * 16;
    float4 v = *reinterpret_cast<const float4*>(&src[(size_t)(r0 + r) * C + c0 + cc]);
    tile[r][cc + 0] = (bf16)v.x; tile[r][cc + 1] = (bf16)v.y;
    tile[r][cc + 2] = (bf16)v.z; tile[r][cc + 3] = (bf16)v.w;
  }
  __syncthreads();
  // write: 8 lanes/dst-row x 8 bf16; 32 dst rows/pass, 2 passes
  int wr = tid >> 3;         // 0..31  dst row (= src col) within block
  int wm = (tid & 7) * 8;    // 0..56  element offset within dst row
#pragma unroll
  for (int i = 0; i < 2; i++) {
    int r = wr + i * 32;
    bf16x8 o;
#pragma unroll
    for (int j = 0; j < 8; j++) o[j] = tile[wm + j][r];
    *reinterpret_cast<bf16x8*>(&dst[(size_t)(c0 + r) * R + r0 + wm]) = o;
  }
}

// -- gating fused with x->bf16 convert: logits -> top2 -> softmax weights --
__global__ void gating_kernel(const float* __restrict__ x,
                              const float* __restrict__ gw,
                              const float* __restrict__ gb,
                              bf16* __restrict__ xb,
                              int* __restrict__ assignE,
                              float2* __restrict__ assignW) {
  int wave = threadIdx.x >> 6, lane = threadIdx.x & 63;
  int t = blockIdx.x * 4 + wave;
  const float* xr = x + (size_t)t * DM;
  // each lane owns 16 contiguous d: [lane*16, lane*16+16)
  float4 xv[4];
  const float4* xr4 = reinterpret_cast<const float4*>(xr) + lane * 4;
#pragma unroll
  for (int i = 0; i < 4; i++) xv[i] = xr4[i];
  // convert + store bf16 x
#pragma unroll
  for (int i = 0; i < 2; i++) {
    float4 a = xv[2 * i], b = xv[2 * i + 1];
    bf16x8 o;
    o[0] = (bf16)a.x; o[1] = (bf16)a.y; o[2] = (bf16)a.z; o[3] = (bf16)a.w;
    o[4] = (bf16)b.x; o[5] = (bf16)b.y; o[6] = (bf16)b.z; o[7] = (bf16)b.w;
    reinterpret_cast<bf16x8*>(xb + (size_t)t * DM)[lane * 2 + i] = o;
  }
  // gate logits
  float acc[8];
#pragma unroll
  for (int e = 0; e < 8; e++) acc[e] = 0.f;
  int d0 = lane * 16;
#pragma unroll
  for (int j = 0; j < 16; j++) {
    float xvj = reinterpret_cast<const float*>(xv)[j];
    const float4* g = reinterpret_cast<const float4*>(gw + (size_t)(d0 + j) * 8);
    float4 g0 = g[0], g1 = g[1];
    acc[0] += xvj * g0.x; acc[1] += xvj * g0.y; acc[2] += xvj * g0.z; acc[3] += xvj * g0.w;
    acc[4] += xvj * g1.x; acc[5] += xvj * g1.y; acc[6] += xvj * g1.z; acc[7] += xvj * g1.w;
  }
#pragma unroll
  for (int off = 32; off > 0; off >>= 1)
#pragma unroll
    for (int e = 0; e < 8; e++) acc[e] += __shfl_xor(acc[e], off, 64);
  if (lane == 0) {
    float v[8];
#pragma unroll
    for (int e = 0; e < 8; e++) v[e] = acc[e] + gb[e];
    int i0 = 0; float v0 = v[0];
#pragma unroll
    for (int e = 1; e < 8; e++) if (v[e] > v0) { v0 = v[e]; i0 = e; }
    int i1 = -1; float v1 = -1e30f;
#pragma unroll
    for (int e = 0; e < 8; e++) if (e != i0 && v[e] > v1) { v1 = v[e]; i1 = e; }
    float p1 = expf(v1 - v0);
    float den = 1.f + p1;
    assignE[t] = i0 | (i1 << 8);
    assignW[t] = make_float2(1.f / den, p1 / den);
  }
}

// ---- router (single block, 512 thr): histogram -> offsets -> LUT -> scatter ----
__global__ void router_kernel(const int* __restrict__ assignE,
                              const float2* __restrict__ assignW,
                              int* __restrict__ rowTok,
                              float* __restrict__ rowW,
                              int2* __restrict__ tokRow,
                              int* __restrict__ tileExpert) {
  __shared__ int cnt[NE], off[NE + 1], cur[NE];
  int tid = threadIdx.x;
  if (tid < NE) cnt[tid] = 0;
  __syncthreads();
  for (int t = tid; t < NTOK; t += 512) {
    int ae = assignE[t];
    atomicAdd(&cnt[ae & 255], 1);
    atomicAdd(&cnt[(ae >> 8) & 255], 1);
  }
  __syncthreads();
  if (tid == 0) {
    int o = 0;
    for (int e = 0; e < NE; e++) { off[e] = o; o += ((cnt[e] + 127) >> 7) << 7; }
    off[NE] = o;
  }
  __syncthreads();
  if (tid < NE) cur[tid] = 0;
  for (int i = tid; i < CAPT; i += 512) {
    int r = i * 128, ex = -1;
#pragma unroll
    for (int e = 0; e < NE; e++)
      if (r >= off[e] && r < off[e + 1]) ex = e;
    tileExpert[i] = ex;
  }
  for (int i = tid; i < CAP; i += 512) { rowTok[i] = -1; rowW[i] = 0.f; }
  __syncthreads();
  for (int t = tid; t < NTOK; t += 512) {
    int ae = assignE[t];
    float2 aw = assignW[t];
    int e0 = ae & 255, e1 = (ae >> 8) & 255;
    int p0 = off[e0] + atomicAdd(&cur[e0], 1);
    rowTok[p0] = t; rowW[p0] = aw.x;
    int p1 = off[e1] + atomicAdd(&cur[e1], 1);
    rowTok[p1] = t; rowW[p1] = aw.y;
    tokRow[t] = make_int2(p0, p1);
  }
}

// ---------------- grouped bf16 MFMA GEMM over expert segments ----------------
// r6-verified config (best measured GEMM2 = 231 us, 0 bank conflicts):
// 2-phase double-buffered K-loop, BM=BN=128, BK=64, 4 waves.
// Swizzle: 16B-slot ^= row&7 (write via pre-swizzled global source, rule #21).
// EPI==0: A gathered via rowTok; Hout[r,n] = gelu(C + bias[n])  (bf16)
// EPI==1: A direct; Y[r][n] = rowW[r] * (C + bias[n])  (fp32, linear)
template <int EPI>
__global__ __launch_bounds__(256) void moe_gemm_kernel(
    const bf16* __restrict__ A, const bf16* __restrict__ Bt,
    const float* __restrict__ bias, bf16* __restrict__ Hout,
    float* __restrict__ Y,
    const int* __restrict__ rowTok, const float* __restrict__ rowW,
    const int* __restrict__ tileExpert,
    int N, int K) {
  constexpr int BM = 128, BN = 128, BK = 64;
  __shared__ __align__(16) bf16 As0[BM * BK];
  __shared__ __align__(16) bf16 Bs0[BN * BK];
  __shared__ __align__(16) bf16 As1[BM * BK];
  __shared__ __align__(16) bf16 Bs1[BN * BK];
  const int tid = threadIdx.x;
  const int wave = tid >> 6, lane = tid & 63;
  const int nbn = N / BN;
  const int bid = (int)blockIdx.x;
  // natural order: XCD = bid % 8 = fixed column stripe -> B-panel L2 affinity
  const int rt = bid / nbn;
  const int e = tileExpert[rt];
  if (e < 0) return;
  const int bm0 = rt * BM;
  const int bn0 = (bid % nbn) * BN;
  const int wm = (wave >> 1) * 64, wn = (wave & 1) * 64;
  const bf16* Be = Bt + (size_t)e * N * K;
  const float* be = bias + (size_t)e * N;

  f32x4 acc[4][4];
#pragma unroll
  for (int m = 0; m < 4; m++)
#pragma unroll
    for (int n = 0; n < 4; n++)
#pragma unroll
      for (int j = 0; j < 4; j++) acc[m][n][j] = 0.f;

  const int srow = lane >> 3;            // 0..7 within an 8-row chunk
  const int scolb = (lane & 7) << 4;     // byte col 0..112

  // hoist per-thread row base pointers (rows fixed across K-loop)
  const char* gaBase[4];
  const char* gbBase[4];
#pragma unroll
  for (int it = 0; it < 4; it++) {
    int chunk = it * 4 + wave;
    int row = chunk * 8 + srow;
    int csw = scolb ^ ((row & 7) << 4);  // pre-swizzled source (rule #21)
    size_t arow;
    if constexpr (EPI == 0) {
      int tok = rowTok[bm0 + row];
      arow = (size_t)(tok < 0 ? 0 : tok);
    } else {
      arow = (size_t)(bm0 + row);
    }
    gaBase[it] = (const char*)A + arow * (size_t)K * 2 + csw;
    gbBase[it] = (const char*)Be + ((size_t)(bn0 + row)) * K * 2 + csw;
  }

  auto STAGE = [&](int kt, bf16* dstA, bf16* dstB) {
#pragma unroll
    for (int it = 0; it < 4; it++) {
      int chunk = it * 4 + wave;
      gload16(gaBase[it] + (size_t)kt * 2, (char*)dstA + chunk * 1024);
      gload16(gbBase[it] + (size_t)kt * 2, (char*)dstB + chunk * 1024);
    }
  };

  auto COMPUTE = [&](const bf16* sA, const bf16* sB) {
#pragma unroll
    for (int kk = 0; kk < 2; kk++) {
      const int kb = kk * 64 + ((lane >> 4) << 4);  // byte offset of k in row
      bf16x8 af[4], bfv[4];
#pragma unroll
      for (int m = 0; m < 4; m++) {
        int r = wm + m * 16 + (lane & 15);
        af[m] = *(const bf16x8*)((const char*)sA + r * 128 + (kb ^ ((r & 7) << 4)));
      }
#pragma unroll
      for (int n = 0; n < 4; n++) {
        int r = wn + n * 16 + (lane & 15);
        bfv[n] = *(const bf16x8*)((const char*)sB + r * 128 + (kb ^ ((r & 7) << 4)));
      }
#pragma unroll
      for (int m = 0; m < 4; m++)
#pragma unroll
        for (int n = 0; n < 4; n++)
          acc[m][n] = __builtin_amdgcn_mfma_f32_16x16x32_bf16(af[m], bfv[n], acc[m][n], 0, 0, 0);
    }
  };

  // prologue: fill buffer 0
  STAGE(0, As0, Bs0);
  __syncthreads();                       // vmcnt(0) + barrier: buf0 ready
  // main loop: 2 K-steps per iteration, static buffer references
  for (int kt = 0; kt < K; kt += 2 * BK) {
    if (kt + BK < K) STAGE(kt + BK, As1, Bs1);   // prefetch into buf1
    COMPUTE(As0, Bs0);
    __syncthreads();                     // buf1 ready; buf0 reads done
    if (kt + 2 * BK < K) STAGE(kt + 2 * BK, As0, Bs0);  // prefetch into buf0
    COMPUTE(As1, Bs1);
    __syncthreads();                     // buf0 ready; buf1 reads done
  }

  const int rb = bm0 + wm + ((lane >> 4) << 2);
  const int cb = bn0 + wn + (lane & 15);
  if constexpr (EPI == 0) {
#pragma unroll
    for (int m = 0; m < 4; m++)
#pragma unroll
      for (int n = 0; n < 4; n++) {
        int c = cb + n * 16;
        float bv = be[c];
#pragma unroll
        for (int j = 0; j < 4; j++) {
          int r = rb + m * 16 + j;
          Hout[(size_t)r * N + c] = (bf16)gelu_f(acc[m][n][j] + bv);
        }
      }
  } else {
#pragma unroll
    for (int m = 0; m < 4; m++) {
#pragma unroll
      for (int j = 0; j < 4; j++) {
        int r = rb + m * 16 + j;
        float w = rowW[r];
        float* yrow = Y + (size_t)r * DM;
#pragma unroll
        for (int n = 0; n < 4; n++) {
          int c = cb + n * 16;
          yrow[c] = w * (acc[m][n][j] + be[c]);
        }
      }
    }
  }
}

// ---------------- combine: out[t] = Y[p0] + Y[p1] ----------------
__global__ void combine_kernel(const float* __restrict__ Y,
                               const int2* __restrict__ tokRow,
                               float* __restrict__ out) {
  int wave = threadIdx.x >> 6, lane = threadIdx.x & 63;
  int t = blockIdx.x * 4 + wave;
  int2 pr = tokRow[t];
  const float4* a = (const float4*)(Y + (size_t)pr.x * DM);
  const float4* b = (const float4*)(Y + (size_t)pr.y * DM);
  float4* o = (float4*)(out + (size_t)t * DM);
#pragma unroll
  for (int i = 0; i < 4; i++) {
    int idx = lane + i * 64;
    float4 u = a[idx], v = b[idx];
    o[idx] = make_float4(u.x + v.x, u.y + v.y, u.z + v.z, u.w + v.w);
  }
}

extern "C" void kernel_launch(void* const* d_in, const int* in_sizes, int n_in,
                              void* d_out, int out_size, void* d_ws, size_t ws_size,
                              hipStream_t stream) {
  const float* x  = (const float*)d_in[0];
  const float* gw = (const float*)d_in[1];
  const float* gb = (const float*)d_in[2];
  const float* w1 = (const float*)d_in[3];
  const float* b1 = (const float*)d_in[4];
  const float* w2 = (const float*)d_in[5];
  const float* b2 = (const float*)d_in[6];
  float* out = (float*)d_out;

  char* p = (char*)d_ws;
  bf16* xb   = (bf16*)p;  p += (size_t)NTOK * DM * 2;      // 16.8 MB (dead after GEMM1)
  bf16* w1t  = (bf16*)p;  p += (size_t)NE * DM * DH * 2;   // 67 MB   (dead after GEMM1)
  bf16* Hg   = (bf16*)p;  p += (size_t)CAP * DH * 2;       // 142.6 MB
  bf16* w2t  = (bf16*)p;  p += (size_t)NE * DM * DH * 2;   // 67 MB  [E][D][H]
  int*   assignE = (int*)p;     p += (size_t)NTOK * 4;
  float2* assignW = (float2*)p; p += (size_t)NTOK * 8;
  int*   rowTok = (int*)p;      p += (size_t)CAP * 4;
  float* rowW   = (float*)p;    p += (size_t)CAP * 4;
  int2*  tokRow = (int2*)p;     p += (size_t)NTOK * 8;
  int*   tileExpert = (int*)p;  p += (size_t)CAPT * 4;
  // Y aliases xb+w1t (71.3 MB <= 83.8 MB; both dead once GEMM2 runs)
  float* Y = (float*)d_ws;

  // w1 [E][DM][DH] -> w1t [E][DH][DM]
  transpose_convert_kernel<<<dim3(DH / 64, DM / 64, NE), 256, 0, stream>>>(w1, w1t, DM, DH);
  // w2 [E][DH][DM] -> w2t [E][DM][DH]
  transpose_convert_kernel<<<dim3(DM / 64, DH / 64, NE), 256, 0, stream>>>(w2, w2t, DH, DM);
  gating_kernel<<<NTOK / 4, 256, 0, stream>>>(x, gw, gb, xb, assignE, assignW);
  router_kernel<<<1, 512, 0, stream>>>(assignE, assignW, rowTok, rowW, tokRow, tileExpert);

  // GEMM1: gathered x @ w1^T -> gelu -> Hg   [CAP x DH]
  moe_gemm_kernel<0><<<CAPT * (DH / 128), 256, 0, stream>>>(
      xb, w1t, b1, Hg, nullptr, rowTok, nullptr, tileExpert, DH, DM);
  // GEMM2: Hg @ w2^T -> Y[r] = w*(y+b2)  (linear, gathered-row space)
  moe_gemm_kernel<1><<<CAPT * (DM / 128), 256, 0, stream>>>(
      Hg, w2t, b2, nullptr, Y, rowTok, rowW, tileExpert, DM, DH);

  combine_kernel<<<NTOK / 4, 256, 0, stream>>>(Y, tokRow, out);
}

// Round 13
// 552.117 us; speedup vs baseline: 1.2322x; 1.0233x over previous
//
#include <hip/hip_runtime.h>
#include <hip/hip_bf16.h>
#include <math.h>

#define NTOK   8192   // B*T = 4*2048
#define DM     1024   // d_model
#define DH     4096   // hidden
#define NE     8      // experts
#define CAP    17408  // max gathered rows: 2*NTOK + 8*127, rounded up to 128
#define CAPT   (CAP/128)   // 136 row-tiles

typedef __bf16 bf16;
typedef __bf16 bf16x4 __attribute__((ext_vector_type(4)));
typedef __bf16 bf16x8 __attribute__((ext_vector_type(8)));
typedef float  f32x4  __attribute__((ext_vector_type(4)));

__device__ __forceinline__ void gload16(const void* g, void* l) {
  __builtin_amdgcn_global_load_lds(
      (const __attribute__((address_space(1))) void*)g,
      (__attribute__((address_space(3))) void*)l, 16, 0, 0);
}

// fast GELU (tanh form)
__device__ __forceinline__ float gelu_f(float v) {
  float u = v * v * v;
  float t = 1.5957691216f * v + 0.0713548162726f * u;
  float e = __expf(-t);
  return v * __builtin_amdgcn_rcpf(1.0f + e);
}

// ---- merged fp32 [E][R][C] -> bf16 [E][C][R] transposes (w1 and w2) ----
// One launch: blocks [0,8192) do w1 (R=DM,C=DH); [8192,16384) do w2 (R=DH,C=DM).
__global__ void transpose_convert2_kernel(const float* __restrict__ w1,
                                          bf16* __restrict__ w1t,
                                          const float* __restrict__ w2,
                                          bf16* __restrict__ w2t) {
  __shared__ bf16 tile[64][66];
  int id = (int)blockIdx.x;
  const float* src; bf16* dst; int R, C;
  if (id < 8192) { src = w1; dst = w1t; R = DM; C = DH; }
  else           { src = w2; dst = w2t; R = DH; C = DM; id -= 8192; }
  int e = id >> 10;            // 1024 blocks per expert
  int rem = id & 1023;
  int nbx = C >> 6;
  int bx = rem % nbx, by = rem / nbx;
  src += (size_t)e * R * C;
  dst += (size_t)e * R * C;
  int c0 = bx * 64, r0 = by * 64;
  int tid = threadIdx.x;
  // read: 16 lanes/row x 4 floats; 16 rows/pass, 4 passes
  int rr = tid >> 4;           // 0..15
  int cc = (tid & 15) * 4;     // 0..60
#pragma unroll
  for (int i = 0; i < 4; i++) {
    int r = rr + i * 16;
    float4 v = *reinterpret_cast<const float4*>(&src[(size_t)(r0 + r) * C + c0 + cc]);
    tile[r][cc + 0] = (bf16)v.x; tile[r][cc + 1] = (bf16)v.y;
    tile[r][cc + 2] = (bf16)v.z; tile[r][cc + 3] = (bf16)v.w;
  }
  __syncthreads();
  // write: 8 lanes/dst-row x 8 bf16; 32 dst rows/pass, 2 passes
  int wr = tid >> 3;           // 0..31  dst row (= src col) within block
  int wm = (tid & 7) * 8;      // 0..56  element offset within dst row
#pragma unroll
  for (int i = 0; i < 2; i++) {
    int r = wr + i * 32;
    bf16x8 o;
#pragma unroll
    for (int j = 0; j < 8; j++) o[j] = tile[wm + j][r];
    *reinterpret_cast<bf16x8*>(&dst[(size_t)(c0 + r) * R + r0 + wm]) = o;
  }
}

// -- gating fused with x->bf16 convert: logits -> top2 -> softmax weights --
__global__ void gating_kernel(const float* __restrict__ x,
                              const float* __restrict__ gw,
                              const float* __restrict__ gb,
                              bf16* __restrict__ xb,
                              int* __restrict__ assignE,
                              float2* __restrict__ assignW) {
  int wave = threadIdx.x >> 6, lane = threadIdx.x & 63;
  int t = blockIdx.x * 4 + wave;
  const float* xr = x + (size_t)t * DM;
  // each lane owns 16 contiguous d: [lane*16, lane*16+16)
  float4 xv[4];
  const float4* xr4 = reinterpret_cast<const float4*>(xr) + lane * 4;
#pragma unroll
  for (int i = 0; i < 4; i++) xv[i] = xr4[i];
  // convert + store bf16 x
#pragma unroll
  for (int i = 0; i < 2; i++) {
    float4 a = xv[2 * i], b = xv[2 * i + 1];
    bf16x8 o;
    o[0] = (bf16)a.x; o[1] = (bf16)a.y; o[2] = (bf16)a.z; o[3] = (bf16)a.w;
    o[4] = (bf16)b.x; o[5] = (bf16)b.y; o[6] = (bf16)b.z; o[7] = (bf16)b.w;
    reinterpret_cast<bf16x8*>(xb + (size_t)t * DM)[lane * 2 + i] = o;
  }
  // gate logits
  float acc[8];
#pragma unroll
  for (int e = 0; e < 8; e++) acc[e] = 0.f;
  int d0 = lane * 16;
#pragma unroll
  for (int j = 0; j < 16; j++) {
    float xvj = reinterpret_cast<const float*>(xv)[j];
    const float4* g = reinterpret_cast<const float4*>(gw + (size_t)(d0 + j) * 8);
    float4 g0 = g[0], g1 = g[1];
    acc[0] += xvj * g0.x; acc[1] += xvj * g0.y; acc[2] += xvj * g0.z; acc[3] += xvj * g0.w;
    acc[4] += xvj * g1.x; acc[5] += xvj * g1.y; acc[6] += xvj * g1.z; acc[7] += xvj * g1.w;
  }
#pragma unroll
  for (int off = 32; off > 0; off >>= 1)
#pragma unroll
    for (int e = 0; e < 8; e++) acc[e] += __shfl_xor(acc[e], off, 64);
  if (lane == 0) {
    float v[8];
#pragma unroll
    for (int e = 0; e < 8; e++) v[e] = acc[e] + gb[e];
    int i0 = 0; float v0 = v[0];
#pragma unroll
    for (int e = 1; e < 8; e++) if (v[e] > v0) { v0 = v[e]; i0 = e; }
    int i1 = -1; float v1 = -1e30f;
#pragma unroll
    for (int e = 0; e < 8; e++) if (e != i0 && v[e] > v1) { v1 = v[e]; i1 = e; }
    float p1 = expf(v1 - v0);
    float den = 1.f + p1;
    assignE[t] = i0 | (i1 << 8);
    assignW[t] = make_float2(1.f / den, p1 / den);
  }
}

// ---- router (single block, 512 thr): histogram -> offsets -> LUT -> scatter ----
__global__ void router_kernel(const int* __restrict__ assignE,
                              const float2* __restrict__ assignW,
                              int* __restrict__ rowTok,
                              float* __restrict__ rowW,
                              int2* __restrict__ tokRow,
                              int* __restrict__ tileExpert) {
  __shared__ int cnt[NE], off[NE + 1], cur[NE];
  int tid = threadIdx.x;
  if (tid < NE) cnt[tid] = 0;
  __syncthreads();
  for (int t = tid; t < NTOK; t += 512) {
    int ae = assignE[t];
    atomicAdd(&cnt[ae & 255], 1);
    atomicAdd(&cnt[(ae >> 8) & 255], 1);
  }
  __syncthreads();
  if (tid == 0) {
    int o = 0;
    for (int e = 0; e < NE; e++) { off[e] = o; o += ((cnt[e] + 127) >> 7) << 7; }
    off[NE] = o;
  }
  __syncthreads();
  if (tid < NE) cur[tid] = 0;
  for (int i = tid; i < CAPT; i += 512) {
    int r = i * 128, ex = -1;
#pragma unroll
    for (int e = 0; e < NE; e++)
      if (r >= off[e] && r < off[e + 1]) ex = e;
    tileExpert[i] = ex;
  }
  for (int i = tid; i < CAP; i += 512) { rowTok[i] = -1; rowW[i] = 0.f; }
  __syncthreads();
  for (int t = tid; t < NTOK; t += 512) {
    int ae = assignE[t];
    float2 aw = assignW[t];
    int e0 = ae & 255, e1 = (ae >> 8) & 255;
    int p0 = off[e0] + atomicAdd(&cur[e0], 1);
    rowTok[p0] = t; rowW[p0] = aw.x;
    int p1 = off[e1] + atomicAdd(&cur[e1], 1);
    rowTok[p1] = t; rowW[p1] = aw.y;
    tokRow[t] = make_int2(p0, p1);
  }
}

// ---------------- grouped bf16 MFMA GEMM over expert segments ----------------
// r6/r12-verified config (best measured; 0 bank conflicts):
// 2-phase double-buffered K-loop, BM=BN=128, BK=64, 4 waves.
// Swizzle: 16B-slot ^= row&7 (write via pre-swizzled global source, rule #21).
// EPI==0: A gathered via rowTok; Hout[r,n] = gelu(C + bias[n])  (bf16)
// EPI==1: A direct; Y[r][n] = rowW[r] * (C + bias[n])  (bf16, linear)
template <int EPI>
__global__ __launch_bounds__(256) void moe_gemm_kernel(
    const bf16* __restrict__ A, const bf16* __restrict__ Bt,
    const float* __restrict__ bias, bf16* __restrict__ Hout,
    bf16* __restrict__ Y,
    const int* __restrict__ rowTok, const float* __restrict__ rowW,
    const int* __restrict__ tileExpert,
    int N, int K) {
  constexpr int BM = 128, BN = 128, BK = 64;
  __shared__ __align__(16) bf16 As0[BM * BK];
  __shared__ __align__(16) bf16 Bs0[BN * BK];
  __shared__ __align__(16) bf16 As1[BM * BK];
  __shared__ __align__(16) bf16 Bs1[BN * BK];
  const int tid = threadIdx.x;
  const int wave = tid >> 6, lane = tid & 63;
  const int nbn = N / BN;
  const int bid = (int)blockIdx.x;
  // natural order: XCD = bid % 8 = fixed column stripe -> B-panel L2 affinity
  const int rt = bid / nbn;
  const int e = tileExpert[rt];
  if (e < 0) return;
  const int bm0 = rt * BM;
  const int bn0 = (bid % nbn) * BN;
  const int wm = (wave >> 1) * 64, wn = (wave & 1) * 64;
  const bf16* Be = Bt + (size_t)e * N * K;
  const float* be = bias + (size_t)e * N;

  f32x4 acc[4][4];
#pragma unroll
  for (int m = 0; m < 4; m++)
#pragma unroll
    for (int n = 0; n < 4; n++)
#pragma unroll
      for (int j = 0; j < 4; j++) acc[m][n][j] = 0.f;

  const int srow = lane >> 3;            // 0..7 within an 8-row chunk
  const int scolb = (lane & 7) << 4;     // byte col 0..112

  // hoist per-thread row base pointers (rows fixed across K-loop)
  const char* gaBase[4];
  const char* gbBase[4];
#pragma unroll
  for (int it = 0; it < 4; it++) {
    int chunk = it * 4 + wave;
    int row = chunk * 8 + srow;
    int csw = scolb ^ ((row & 7) << 4);  // pre-swizzled source (rule #21)
    size_t arow;
    if constexpr (EPI == 0) {
      int tok = rowTok[bm0 + row];
      arow = (size_t)(tok < 0 ? 0 : tok);
    } else {
      arow = (size_t)(bm0 + row);
    }
    gaBase[it] = (const char*)A + arow * (size_t)K * 2 + csw;
    gbBase[it] = (const char*)Be + ((size_t)(bn0 + row)) * K * 2 + csw;
  }

  auto STAGE = [&](int kt, bf16* dstA, bf16* dstB) {
#pragma unroll
    for (int it = 0; it < 4; it++) {
      int chunk = it * 4 + wave;
      gload16(gaBase[it] + (size_t)kt * 2, (char*)dstA + chunk * 1024);
      gload16(gbBase[it] + (size_t)kt * 2, (char*)dstB + chunk * 1024);
    }
  };

  auto COMPUTE = [&](const bf16* sA, const bf16* sB) {
#pragma unroll
    for (int kk = 0; kk < 2; kk++) {
      const int kb = kk * 64 + ((lane >> 4) << 4);  // byte offset of k in row
      bf16x8 af[4], bfv[4];
#pragma unroll
      for (int m = 0; m < 4; m++) {
        int r = wm + m * 16 + (lane & 15);
        af[m] = *(const bf16x8*)((const char*)sA + r * 128 + (kb ^ ((r & 7) << 4)));
      }
#pragma unroll
      for (int n = 0; n < 4; n++) {
        int r = wn + n * 16 + (lane & 15);
        bfv[n] = *(const bf16x8*)((const char*)sB + r * 128 + (kb ^ ((r & 7) << 4)));
      }
#pragma unroll
      for (int m = 0; m < 4; m++)
#pragma unroll
        for (int n = 0; n < 4; n++)
          acc[m][n] = __builtin_amdgcn_mfma_f32_16x16x32_bf16(af[m], bfv[n], acc[m][n], 0, 0, 0);
    }
  };

  // prologue: fill buffer 0
  STAGE(0, As0, Bs0);
  __syncthreads();                       // vmcnt(0) + barrier: buf0 ready
  // main loop: 2 K-steps per iteration, static buffer references
  for (int kt = 0; kt < K; kt += 2 * BK) {
    if (kt + BK < K) STAGE(kt + BK, As1, Bs1);   // prefetch into buf1
    COMPUTE(As0, Bs0);
    __syncthreads();                     // buf1 ready; buf0 reads done
    if (kt + 2 * BK < K) STAGE(kt + 2 * BK, As0, Bs0);  // prefetch into buf0
    COMPUTE(As1, Bs1);
    __syncthreads();                     // buf0 ready; buf1 reads done
  }

  const int rb = bm0 + wm + ((lane >> 4) << 2);
  const int cb = bn0 + wn + (lane & 15);
  if constexpr (EPI == 0) {
#pragma unroll
    for (int m = 0; m < 4; m++)
#pragma unroll
      for (int n = 0; n < 4; n++) {
        int c = cb + n * 16;
        float bv = be[c];
#pragma unroll
        for (int j = 0; j < 4; j++) {
          int r = rb + m * 16 + j;
          Hout[(size_t)r * N + c] = (bf16)gelu_f(acc[m][n][j] + bv);
        }
      }
  } else {
#pragma unroll
    for (int m = 0; m < 4; m++) {
#pragma unroll
      for (int j = 0; j < 4; j++) {
        int r = rb + m * 16 + j;
        float w = rowW[r];
        bf16* yrow = Y + (size_t)r * DM;
#pragma unroll
        for (int n = 0; n < 4; n++) {
          int c = cb + n * 16;
          yrow[c] = (bf16)(w * (acc[m][n][j] + be[c]));
        }
      }
    }
  }
}

// ---------------- combine: out[t] = Y[p0] + Y[p1]  (bf16 in, fp32 out) ----------------
__global__ void combine_kernel(const bf16* __restrict__ Y,
                               const int2* __restrict__ tokRow,
                               float* __restrict__ out) {
  int wave = threadIdx.x >> 6, lane = threadIdx.x & 63;
  int t = blockIdx.x * 4 + wave;
  int2 pr = tokRow[t];
  const bf16x8* a = (const bf16x8*)(Y + (size_t)pr.x * DM);
  const bf16x8* b = (const bf16x8*)(Y + (size_t)pr.y * DM);
  float4* o = (float4*)(out + (size_t)t * DM);
#pragma unroll
  for (int i = 0; i < 2; i++) {
    int idx = lane + i * 64;   // 8-elem chunk index (128 chunks per row)
    bf16x8 u = a[idx], v = b[idx];
    float4 s0, s1;
    s0.x = (float)u[0] + (float)v[0]; s0.y = (float)u[1] + (float)v[1];
    s0.z = (float)u[2] + (float)v[2]; s0.w = (float)u[3] + (float)v[3];
    s1.x = (float)u[4] + (float)v[4]; s1.y = (float)u[5] + (float)v[5];
    s1.z = (float)u[6] + (float)v[6]; s1.w = (float)u[7] + (float)v[7];
    o[idx * 2] = s0;
    o[idx * 2 + 1] = s1;
  }
}

extern "C" void kernel_launch(void* const* d_in, const int* in_sizes, int n_in,
                              void* d_out, int out_size, void* d_ws, size_t ws_size,
                              hipStream_t stream) {
  const float* x  = (const float*)d_in[0];
  const float* gw = (const float*)d_in[1];
  const float* gb = (const float*)d_in[2];
  const float* w1 = (const float*)d_in[3];
  const float* b1 = (const float*)d_in[4];
  const float* w2 = (const float*)d_in[5];
  const float* b2 = (const float*)d_in[6];
  float* out = (float*)d_out;

  char* p = (char*)d_ws;
  bf16* xb   = (bf16*)p;  p += (size_t)NTOK * DM * 2;      // 16.8 MB (dead after GEMM1)
  bf16* w1t  = (bf16*)p;  p += (size_t)NE * DM * DH * 2;   // 67 MB   (dead after GEMM1)
  bf16* Hg   = (bf16*)p;  p += (size_t)CAP * DH * 2;       // 142.6 MB
  bf16* w2t  = (bf16*)p;  p += (size_t)NE * DM * DH * 2;   // 67 MB  [E][D][H]
  int*   assignE = (int*)p;     p += (size_t)NTOK * 4;
  float2* assignW = (float2*)p; p += (size_t)NTOK * 8;
  int*   rowTok = (int*)p;      p += (size_t)CAP * 4;
  float* rowW   = (float*)p;    p += (size_t)CAP * 4;
  int2*  tokRow = (int2*)p;     p += (size_t)NTOK * 8;
  int*   tileExpert = (int*)p;  p += (size_t)CAPT * 4;
  // Y (bf16, 35.7 MB) aliases xb+w1t (83.8 MB; both dead once GEMM2 runs)
  bf16* Y = (bf16*)d_ws;

  // merged transposes: w1 -> w1t [E][DH][DM], w2 -> w2t [E][DM][DH]
  transpose_convert2_kernel<<<16384, 256, 0, stream>>>(w1, w1t, w2, w2t);
  gating_kernel<<<NTOK / 4, 256, 0, stream>>>(x, gw, gb, xb, assignE, assignW);
  router_kernel<<<1, 512, 0, stream>>>(assignE, assignW, rowTok, rowW, tokRow, tileExpert);

  // GEMM1: gathered x @ w1^T -> gelu -> Hg   [CAP x DH]
  moe_gemm_kernel<0><<<CAPT * (DH / 128), 256, 0, stream>>>(
      xb, w1t, b1, Hg, nullptr, rowTok, nullptr, tileExpert, DH, DM);
  // GEMM2: Hg @ w2^T -> Y[r] = w*(y+b2)  (bf16, linear, gathered-row space)
  moe_gemm_kernel<1><<<CAPT * (DM / 128), 256, 0, stream>>>(
      Hg, w2t, b2, nullptr, Y, rowTok, rowW, tileExpert, DM, DH);

  combine_kernel<<<NTOK / 4, 256, 0, stream>>>(Y, tokRow, out);
}

// Round 14
// 551.163 us; speedup vs baseline: 1.2344x; 1.0017x over previous
//
#include <hip/hip_runtime.h>
#include <hip/hip_bf16.h>
#include <math.h>

#define NTOK   8192   // B*T = 4*2048
#define DM     1024   // d_model
#define DH     4096   // hidden
#define NE     8      // experts
#define CAP    17408  // max gathered rows: 2*NTOK + 8*127, rounded up to 128
#define CAPT   (CAP/128)   // 136 row-tiles

typedef __bf16 bf16;
typedef __bf16 bf16x4 __attribute__((ext_vector_type(4)));
typedef __bf16 bf16x8 __attribute__((ext_vector_type(8)));
typedef float  f32x4  __attribute__((ext_vector_type(4)));

__device__ __forceinline__ void gload16(const void* g, void* l) {
  __builtin_amdgcn_global_load_lds(
      (const __attribute__((address_space(1))) void*)g,
      (__attribute__((address_space(3))) void*)l, 16, 0, 0);
}

// fast GELU (tanh form)
__device__ __forceinline__ float gelu_f(float v) {
  float u = v * v * v;
  float t = 1.5957691216f * v + 0.0713548162726f * u;
  float e = __expf(-t);
  return v * __builtin_amdgcn_rcpf(1.0f + e);
}

// ---- merged fp32 [E][R][C] -> bf16 [E][C][R] transposes (w1 and w2) ----
// One launch: blocks [0,8192) do w1 (R=DM,C=DH); [8192,16384) do w2 (R=DH,C=DM).
__global__ void transpose_convert2_kernel(const float* __restrict__ w1,
                                          bf16* __restrict__ w1t,
                                          const float* __restrict__ w2,
                                          bf16* __restrict__ w2t) {
  __shared__ bf16 tile[64][66];
  int id = (int)blockIdx.x;
  const float* src; bf16* dst; int R, C;
  if (id < 8192) { src = w1; dst = w1t; R = DM; C = DH; }
  else           { src = w2; dst = w2t; R = DH; C = DM; id -= 8192; }
  int e = id >> 10;            // 1024 blocks per expert
  int rem = id & 1023;
  int nbx = C >> 6;
  int bx = rem % nbx, by = rem / nbx;
  src += (size_t)e * R * C;
  dst += (size_t)e * R * C;
  int c0 = bx * 64, r0 = by * 64;
  int tid = threadIdx.x;
  // read: 16 lanes/row x 4 floats; 16 rows/pass, 4 passes
  int rr = tid >> 4;           // 0..15
  int cc = (tid & 15) * 4;     // 0..60
#pragma unroll
  for (int i = 0; i < 4; i++) {
    int r = rr + i * 16;
    float4 v = *reinterpret_cast<const float4*>(&src[(size_t)(r0 + r) * C + c0 + cc]);
    tile[r][cc + 0] = (bf16)v.x; tile[r][cc + 1] = (bf16)v.y;
    tile[r][cc + 2] = (bf16)v.z; tile[r][cc + 3] = (bf16)v.w;
  }
  __syncthreads();
  // write: 8 lanes/dst-row x 8 bf16; 32 dst rows/pass, 2 passes
  int wr = tid >> 3;           // 0..31  dst row (= src col) within block
  int wm = (tid & 7) * 8;      // 0..56  element offset within dst row
#pragma unroll
  for (int i = 0; i < 2; i++) {
    int r = wr + i * 32;
    bf16x8 o;
#pragma unroll
    for (int j = 0; j < 8; j++) o[j] = tile[wm + j][r];
    *reinterpret_cast<bf16x8*>(&dst[(size_t)(c0 + r) * R + r0 + wm]) = o;
  }
}

// -- gating fused with x->bf16 convert: logits -> top2 -> softmax weights --
__global__ void gating_kernel(const float* __restrict__ x,
                              const float* __restrict__ gw,
                              const float* __restrict__ gb,
                              bf16* __restrict__ xb,
                              int* __restrict__ assignE,
                              float2* __restrict__ assignW) {
  int wave = threadIdx.x >> 6, lane = threadIdx.x & 63;
  int t = blockIdx.x * 4 + wave;
  const float* xr = x + (size_t)t * DM;
  // each lane owns 16 contiguous d: [lane*16, lane*16+16)
  float4 xv[4];
  const float4* xr4 = reinterpret_cast<const float4*>(xr) + lane * 4;
#pragma unroll
  for (int i = 0; i < 4; i++) xv[i] = xr4[i];
  // convert + store bf16 x
#pragma unroll
  for (int i = 0; i < 2; i++) {
    float4 a = xv[2 * i], b = xv[2 * i + 1];
    bf16x8 o;
    o[0] = (bf16)a.x; o[1] = (bf16)a.y; o[2] = (bf16)a.z; o[3] = (bf16)a.w;
    o[4] = (bf16)b.x; o[5] = (bf16)b.y; o[6] = (bf16)b.z; o[7] = (bf16)b.w;
    reinterpret_cast<bf16x8*>(xb + (size_t)t * DM)[lane * 2 + i] = o;
  }
  // gate logits
  float acc[8];
#pragma unroll
  for (int e = 0; e < 8; e++) acc[e] = 0.f;
  int d0 = lane * 16;
#pragma unroll
  for (int j = 0; j < 16; j++) {
    float xvj = reinterpret_cast<const float*>(xv)[j];
    const float4* g = reinterpret_cast<const float4*>(gw + (size_t)(d0 + j) * 8);
    float4 g0 = g[0], g1 = g[1];
    acc[0] += xvj * g0.x; acc[1] += xvj * g0.y; acc[2] += xvj * g0.z; acc[3] += xvj * g0.w;
    acc[4] += xvj * g1.x; acc[5] += xvj * g1.y; acc[6] += xvj * g1.z; acc[7] += xvj * g1.w;
  }
#pragma unroll
  for (int off = 32; off > 0; off >>= 1)
#pragma unroll
    for (int e = 0; e < 8; e++) acc[e] += __shfl_xor(acc[e], off, 64);
  if (lane == 0) {
    float v[8];
#pragma unroll
    for (int e = 0; e < 8; e++) v[e] = acc[e] + gb[e];
    int i0 = 0; float v0 = v[0];
#pragma unroll
    for (int e = 1; e < 8; e++) if (v[e] > v0) { v0 = v[e]; i0 = e; }
    int i1 = -1; float v1 = -1e30f;
#pragma unroll
    for (int e = 0; e < 8; e++) if (e != i0 && v[e] > v1) { v1 = v[e]; i1 = e; }
    float p1 = expf(v1 - v0);
    float den = 1.f + p1;
    assignE[t] = i0 | (i1 << 8);
    assignW[t] = make_float2(1.f / den, p1 / den);
  }
}

// ---- router (single block, 512 thr): histogram -> offsets -> LUT -> scatter ----
__global__ void router_kernel(const int* __restrict__ assignE,
                              const float2* __restrict__ assignW,
                              int* __restrict__ rowTok,
                              float* __restrict__ rowW,
                              int2* __restrict__ tokRow,
                              int* __restrict__ tileExpert) {
  __shared__ int cnt[NE], off[NE + 1], cur[NE];
  int tid = threadIdx.x;
  if (tid < NE) cnt[tid] = 0;
  __syncthreads();
  for (int t = tid; t < NTOK; t += 512) {
    int ae = assignE[t];
    atomicAdd(&cnt[ae & 255], 1);
    atomicAdd(&cnt[(ae >> 8) & 255], 1);
  }
  __syncthreads();
  if (tid == 0) {
    int o = 0;
    for (int e = 0; e < NE; e++) { off[e] = o; o += ((cnt[e] + 127) >> 7) << 7; }
    off[NE] = o;
  }
  __syncthreads();
  if (tid < NE) cur[tid] = 0;
  for (int i = tid; i < CAPT; i += 512) {
    int r = i * 128, ex = -1;
#pragma unroll
    for (int e = 0; e < NE; e++)
      if (r >= off[e] && r < off[e + 1]) ex = e;
    tileExpert[i] = ex;
  }
  for (int i = tid; i < CAP; i += 512) { rowTok[i] = -1; rowW[i] = 0.f; }
  __syncthreads();
  for (int t = tid; t < NTOK; t += 512) {
    int ae = assignE[t];
    float2 aw = assignW[t];
    int e0 = ae & 255, e1 = (ae >> 8) & 255;
    int p0 = off[e0] + atomicAdd(&cur[e0], 1);
    rowTok[p0] = t; rowW[p0] = aw.x;
    int p1 = off[e1] + atomicAdd(&cur[e1], 1);
    rowTok[p1] = t; rowW[p1] = aw.y;
    tokRow[t] = make_int2(p0, p1);
  }
}

// ---------------- grouped bf16 MFMA GEMM over expert segments ----------------
// r6/r12-verified config (best measured; 0 bank conflicts):
// 2-phase double-buffered K-loop, BM=BN=128, BK=64, 4 waves.
// Swizzle: 16B-slot ^= row&7 (write via pre-swizzled global source, rule #21).
// EPI==1 reverses row-tile order: GEMM1 wrote Hg rows ascending, so L3 holds
// the TAIL of Hg; reading freshest-first (descending) converts the sequential
// re-scan LRU worst case into hits. bid%nbn (XCD column affinity) unchanged.
// EPI==0: A gathered via rowTok; Hout[r,n] = gelu(C + bias[n])  (bf16)
// EPI==1: A direct; Y[r][n] = rowW[r] * (C + bias[n])  (bf16, linear)
template <int EPI>
__global__ __launch_bounds__(256) void moe_gemm_kernel(
    const bf16* __restrict__ A, const bf16* __restrict__ Bt,
    const float* __restrict__ bias, bf16* __restrict__ Hout,
    bf16* __restrict__ Y,
    const int* __restrict__ rowTok, const float* __restrict__ rowW,
    const int* __restrict__ tileExpert,
    int N, int K) {
  constexpr int BM = 128, BN = 128, BK = 64;
  __shared__ __align__(16) bf16 As0[BM * BK];
  __shared__ __align__(16) bf16 Bs0[BN * BK];
  __shared__ __align__(16) bf16 As1[BM * BK];
  __shared__ __align__(16) bf16 Bs1[BN * BK];
  const int tid = threadIdx.x;
  const int wave = tid >> 6, lane = tid & 63;
  const int nbn = N / BN;
  const int bid = (int)blockIdx.x;
  // natural col order: XCD = bid % 8 = fixed column stripe -> B-panel L2 affinity
  int rt = bid / nbn;
  if constexpr (EPI == 1) rt = (CAPT - 1) - rt;   // reverse scan (L3 LRU)
  const int e = tileExpert[rt];
  if (e < 0) return;
  const int bm0 = rt * BM;
  const int bn0 = (bid % nbn) * BN;
  const int wm = (wave >> 1) * 64, wn = (wave & 1) * 64;
  const bf16* Be = Bt + (size_t)e * N * K;
  const float* be = bias + (size_t)e * N;

  f32x4 acc[4][4];
#pragma unroll
  for (int m = 0; m < 4; m++)
#pragma unroll
    for (int n = 0; n < 4; n++)
#pragma unroll
      for (int j = 0; j < 4; j++) acc[m][n][j] = 0.f;

  const int srow = lane >> 3;            // 0..7 within an 8-row chunk
  const int scolb = (lane & 7) << 4;     // byte col 0..112

  // hoist per-thread row base pointers (rows fixed across K-loop)
  const char* gaBase[4];
  const char* gbBase[4];
#pragma unroll
  for (int it = 0; it < 4; it++) {
    int chunk = it * 4 + wave;
    int row = chunk * 8 + srow;
    int csw = scolb ^ ((row & 7) << 4);  // pre-swizzled source (rule #21)
    size_t arow;
    if constexpr (EPI == 0) {
      int tok = rowTok[bm0 + row];
      arow = (size_t)(tok < 0 ? 0 : tok);
    } else {
      arow = (size_t)(bm0 + row);
    }
    gaBase[it] = (const char*)A + arow * (size_t)K * 2 + csw;
    gbBase[it] = (const char*)Be + ((size_t)(bn0 + row)) * K * 2 + csw;
  }

  auto STAGE = [&](int kt, bf16* dstA, bf16* dstB) {
#pragma unroll
    for (int it = 0; it < 4; it++) {
      int chunk = it * 4 + wave;
      gload16(gaBase[it] + (size_t)kt * 2, (char*)dstA + chunk * 1024);
      gload16(gbBase[it] + (size_t)kt * 2, (char*)dstB + chunk * 1024);
    }
  };

  auto COMPUTE = [&](const bf16* sA, const bf16* sB) {
#pragma unroll
    for (int kk = 0; kk < 2; kk++) {
      const int kb = kk * 64 + ((lane >> 4) << 4);  // byte offset of k in row
      bf16x8 af[4], bfv[4];
#pragma unroll
      for (int m = 0; m < 4; m++) {
        int r = wm + m * 16 + (lane & 15);
        af[m] = *(const bf16x8*)((const char*)sA + r * 128 + (kb ^ ((r & 7) << 4)));
      }
#pragma unroll
      for (int n = 0; n < 4; n++) {
        int r = wn + n * 16 + (lane & 15);
        bfv[n] = *(const bf16x8*)((const char*)sB + r * 128 + (kb ^ ((r & 7) << 4)));
      }
#pragma unroll
      for (int m = 0; m < 4; m++)
#pragma unroll
        for (int n = 0; n < 4; n++)
          acc[m][n] = __builtin_amdgcn_mfma_f32_16x16x32_bf16(af[m], bfv[n], acc[m][n], 0, 0, 0);
    }
  };

  // prologue: fill buffer 0
  STAGE(0, As0, Bs0);
  __syncthreads();                       // vmcnt(0) + barrier: buf0 ready
  // main loop: 2 K-steps per iteration, static buffer references
  for (int kt = 0; kt < K; kt += 2 * BK) {
    if (kt + BK < K) STAGE(kt + BK, As1, Bs1);   // prefetch into buf1
    COMPUTE(As0, Bs0);
    __syncthreads();                     // buf1 ready; buf0 reads done
    if (kt + 2 * BK < K) STAGE(kt + 2 * BK, As0, Bs0);  // prefetch into buf0
    COMPUTE(As1, Bs1);
    __syncthreads();                     // buf0 ready; buf1 reads done
  }

  const int rb = bm0 + wm + ((lane >> 4) << 2);
  const int cb = bn0 + wn + (lane & 15);
  if constexpr (EPI == 0) {
#pragma unroll
    for (int m = 0; m < 4; m++)
#pragma unroll
      for (int n = 0; n < 4; n++) {
        int c = cb + n * 16;
        float bv = be[c];
#pragma unroll
        for (int j = 0; j < 4; j++) {
          int r = rb + m * 16 + j;
          Hout[(size_t)r * N + c] = (bf16)gelu_f(acc[m][n][j] + bv);
        }
      }
  } else {
#pragma unroll
    for (int m = 0; m < 4; m++) {
#pragma unroll
      for (int j = 0; j < 4; j++) {
        int r = rb + m * 16 + j;
        float w = rowW[r];
        bf16* yrow = Y + (size_t)r * DM;
#pragma unroll
        for (int n = 0; n < 4; n++) {
          int c = cb + n * 16;
          yrow[c] = (bf16)(w * (acc[m][n][j] + be[c]));
        }
      }
    }
  }
}

// ---------------- combine: out[t] = Y[p0] + Y[p1]  (bf16 in, fp32 out) ----------------
__global__ void combine_kernel(const bf16* __restrict__ Y,
                               const int2* __restrict__ tokRow,
                               float* __restrict__ out) {
  int wave = threadIdx.x >> 6, lane = threadIdx.x & 63;
  int t = blockIdx.x * 4 + wave;
  int2 pr = tokRow[t];
  const bf16x8* a = (const bf16x8*)(Y + (size_t)pr.x * DM);
  const bf16x8* b = (const bf16x8*)(Y + (size_t)pr.y * DM);
  float4* o = (float4*)(out + (size_t)t * DM);
#pragma unroll
  for (int i = 0; i < 2; i++) {
    int idx = lane + i * 64;   // 8-elem chunk index (128 chunks per row)
    bf16x8 u = a[idx], v = b[idx];
    float4 s0, s1;
    s0.x = (float)u[0] + (float)v[0]; s0.y = (float)u[1] + (float)v[1];
    s0.z = (float)u[2] + (float)v[2]; s0.w = (float)u[3] + (float)v[3];
    s1.x = (float)u[4] + (float)v[4]; s1.y = (float)u[5] + (float)v[5];
    s1.z = (float)u[6] + (float)v[6]; s1.w = (float)u[7] + (float)v[7];
    o[idx * 2] = s0;
    o[idx * 2 + 1] = s1;
  }
}

extern "C" void kernel_launch(void* const* d_in, const int* in_sizes, int n_in,
                              void* d_out, int out_size, void* d_ws, size_t ws_size,
                              hipStream_t stream) {
  const float* x  = (const float*)d_in[0];
  const float* gw = (const float*)d_in[1];
  const float* gb = (const float*)d_in[2];
  const float* w1 = (const float*)d_in[3];
  const float* b1 = (const float*)d_in[4];
  const float* w2 = (const float*)d_in[5];
  const float* b2 = (const float*)d_in[6];
  float* out = (float*)d_out;

  char* p = (char*)d_ws;
  bf16* xb   = (bf16*)p;  p += (size_t)NTOK * DM * 2;      // 16.8 MB (dead after GEMM1)
  bf16* w1t  = (bf16*)p;  p += (size_t)NE * DM * DH * 2;   // 67 MB   (dead after GEMM1)
  bf16* Hg   = (bf16*)p;  p += (size_t)CAP * DH * 2;       // 142.6 MB
  bf16* w2t  = (bf16*)p;  p += (size_t)NE * DM * DH * 2;   // 67 MB  [E][D][H]
  int*   assignE = (int*)p;     p += (size_t)NTOK * 4;
  float2* assignW = (float2*)p; p += (size_t)NTOK * 8;
  int*   rowTok = (int*)p;      p += (size_t)CAP * 4;
  float* rowW   = (float*)p;    p += (size_t)CAP * 4;
  int2*  tokRow = (int2*)p;     p += (size_t)NTOK * 8;
  int*   tileExpert = (int*)p;  p += (size_t)CAPT * 4;
  // Y (bf16, 35.7 MB) aliases xb+w1t (83.8 MB; both dead once GEMM2 runs)
  bf16* Y = (bf16*)d_ws;

  // merged transposes: w1 -> w1t [E][DH][DM], w2 -> w2t [E][DM][DH]
  transpose_convert2_kernel<<<16384, 256, 0, stream>>>(w1, w1t, w2, w2t);
  gating_kernel<<<NTOK / 4, 256, 0, stream>>>(x, gw, gb, xb, assignE, assignW);
  router_kernel<<<1, 512, 0, stream>>>(assignE, assignW, rowTok, rowW, tokRow, tileExpert);

  // GEMM1: gathered x @ w1^T -> gelu -> Hg   [CAP x DH]
  moe_gemm_kernel<0><<<CAPT * (DH / 128), 256, 0, stream>>>(
      xb, w1t, b1, Hg, nullptr, rowTok, nullptr, tileExpert, DH, DM);
  // GEMM2: Hg @ w2^T -> Y[r] = w*(y+b2)  (bf16, linear, reverse row scan)
  moe_gemm_kernel<1><<<CAPT * (DM / 128), 256, 0, stream>>>(
      Hg, w2t, b2, nullptr, Y, rowTok, rowW, tileExpert, DM, DH);

  combine_kernel<<<NTOK / 4, 256, 0, stream>>>(Y, tokRow, out);
}

// Round 15
// 538.749 us; speedup vs baseline: 1.2628x; 1.0230x over previous
//
#include <hip/hip_runtime.h>
#include <hip/hip_bf16.h>
#include <math.h>

#define NTOK   8192   // B*T = 4*2048
#define DM     1024   // d_model
#define DH     4096   // hidden
#define NE     8      // experts
#define CAP    18432  // max gathered rows: 2*8192 + 8*255, rounded up to 256
#define NTIL   (CAP/256)   // 72 row-tiles of 256 (GEMM1)
#define CAPT   (CAP/128)   // 144 row-tiles of 128 (GEMM2)

typedef __bf16 bf16;
typedef __bf16 bf16x4 __attribute__((ext_vector_type(4)));
typedef __bf16 bf16x8 __attribute__((ext_vector_type(8)));
typedef float  f32x4  __attribute__((ext_vector_type(4)));

__device__ __forceinline__ void gload16(const void* g, void* l) {
  __builtin_amdgcn_global_load_lds(
      (const __attribute__((address_space(1))) void*)g,
      (__attribute__((address_space(3))) void*)l, 16, 0, 0);
}

#define BAR()   asm volatile("s_barrier" ::: "memory")
#define LGKM0() asm volatile("s_waitcnt lgkmcnt(0)" ::: "memory")
#define VM4()   asm volatile("s_waitcnt vmcnt(4)" ::: "memory")
#define VM0()   asm volatile("s_waitcnt vmcnt(0)" ::: "memory")

// fast GELU (tanh form)
__device__ __forceinline__ float gelu_f(float v) {
  float u = v * v * v;
  float t = 1.5957691216f * v + 0.0713548162726f * u;
  float e = __expf(-t);
  return v * __builtin_amdgcn_rcpf(1.0f + e);
}

// ---- merged fp32 [E][R][C] -> bf16 [E][C][R] transposes (w1 and w2) ----
__global__ void transpose_convert2_kernel(const float* __restrict__ w1,
                                          bf16* __restrict__ w1t,
                                          const float* __restrict__ w2,
                                          bf16* __restrict__ w2t) {
  __shared__ bf16 tile[64][66];
  int id = (int)blockIdx.x;
  const float* src; bf16* dst; int R, C;
  if (id < 8192) { src = w1; dst = w1t; R = DM; C = DH; }
  else           { src = w2; dst = w2t; R = DH; C = DM; id -= 8192; }
  int e = id >> 10;
  int rem = id & 1023;
  int nbx = C >> 6;
  int bx = rem % nbx, by = rem / nbx;
  src += (size_t)e * R * C;
  dst += (size_t)e * R * C;
  int c0 = bx * 64, r0 = by * 64;
  int tid = threadIdx.x;
  int rr = tid >> 4;
  int cc = (tid & 15) * 4;
#pragma unroll
  for (int i = 0; i < 4; i++) {
    int r = rr + i * 16;
    float4 v = *reinterpret_cast<const float4*>(&src[(size_t)(r0 + r) * C + c0 + cc]);
    tile[r][cc + 0] = (bf16)v.x; tile[r][cc + 1] = (bf16)v.y;
    tile[r][cc + 2] = (bf16)v.z; tile[r][cc + 3] = (bf16)v.w;
  }
  __syncthreads();
  int wr = tid >> 3;
  int wm = (tid & 7) * 8;
#pragma unroll
  for (int i = 0; i < 2; i++) {
    int r = wr + i * 32;
    bf16x8 o;
#pragma unroll
    for (int j = 0; j < 8; j++) o[j] = tile[wm + j][r];
    *reinterpret_cast<bf16x8*>(&dst[(size_t)(c0 + r) * R + r0 + wm]) = o;
  }
}

// -- gating fused with x->bf16 convert --
__global__ void gating_kernel(const float* __restrict__ x,
                              const float* __restrict__ gw,
                              const float* __restrict__ gb,
                              bf16* __restrict__ xb,
                              int* __restrict__ assignE,
                              float2* __restrict__ assignW) {
  int wave = threadIdx.x >> 6, lane = threadIdx.x & 63;
  int t = blockIdx.x * 4 + wave;
  const float* xr = x + (size_t)t * DM;
  float4 xv[4];
  const float4* xr4 = reinterpret_cast<const float4*>(xr) + lane * 4;
#pragma unroll
  for (int i = 0; i < 4; i++) xv[i] = xr4[i];
#pragma unroll
  for (int i = 0; i < 2; i++) {
    float4 a = xv[2 * i], b = xv[2 * i + 1];
    bf16x8 o;
    o[0] = (bf16)a.x; o[1] = (bf16)a.y; o[2] = (bf16)a.z; o[3] = (bf16)a.w;
    o[4] = (bf16)b.x; o[5] = (bf16)b.y; o[6] = (bf16)b.z; o[7] = (bf16)b.w;
    reinterpret_cast<bf16x8*>(xb + (size_t)t * DM)[lane * 2 + i] = o;
  }
  float acc[8];
#pragma unroll
  for (int e = 0; e < 8; e++) acc[e] = 0.f;
  int d0 = lane * 16;
#pragma unroll
  for (int j = 0; j < 16; j++) {
    float xvj = reinterpret_cast<const float*>(xv)[j];
    const float4* g = reinterpret_cast<const float4*>(gw + (size_t)(d0 + j) * 8);
    float4 g0 = g[0], g1 = g[1];
    acc[0] += xvj * g0.x; acc[1] += xvj * g0.y; acc[2] += xvj * g0.z; acc[3] += xvj * g0.w;
    acc[4] += xvj * g1.x; acc[5] += xvj * g1.y; acc[6] += xvj * g1.z; acc[7] += xvj * g1.w;
  }
#pragma unroll
  for (int off = 32; off > 0; off >>= 1)
#pragma unroll
    for (int e = 0; e < 8; e++) acc[e] += __shfl_xor(acc[e], off, 64);
  if (lane == 0) {
    float v[8];
#pragma unroll
    for (int e = 0; e < 8; e++) v[e] = acc[e] + gb[e];
    int i0 = 0; float v0 = v[0];
#pragma unroll
    for (int e = 1; e < 8; e++) if (v[e] > v0) { v0 = v[e]; i0 = e; }
    int i1 = -1; float v1 = -1e30f;
#pragma unroll
    for (int e = 0; e < 8; e++) if (e != i0 && v[e] > v1) { v1 = v[e]; i1 = e; }
    float p1 = expf(v1 - v0);
    float den = 1.f + p1;
    assignE[t] = i0 | (i1 << 8);
    assignW[t] = make_float2(1.f / den, p1 / den);
  }
}

// ---- router: 256-aligned segments (serve both 256- and 128-tiling) ----
__global__ void router_kernel(const int* __restrict__ assignE,
                              const float2* __restrict__ assignW,
                              int* __restrict__ rowTok,
                              float* __restrict__ rowW,
                              int2* __restrict__ tokRow,
                              int* __restrict__ tileExpert) {
  __shared__ int cnt[NE], off[NE + 1], cur[NE];
  int tid = threadIdx.x;
  if (tid < NE) cnt[tid] = 0;
  __syncthreads();
  for (int t = tid; t < NTOK; t += 512) {
    int ae = assignE[t];
    atomicAdd(&cnt[ae & 255], 1);
    atomicAdd(&cnt[(ae >> 8) & 255], 1);
  }
  __syncthreads();
  if (tid == 0) {
    int o = 0;
    for (int e = 0; e < NE; e++) { off[e] = o; o += ((cnt[e] + 255) >> 8) << 8; }
    off[NE] = o;
  }
  __syncthreads();
  if (tid < NE) cur[tid] = 0;
  for (int i = tid; i < CAPT; i += 512) {
    int r = i * 128, ex = -1;
#pragma unroll
    for (int e = 0; e < NE; e++)
      if (r >= off[e] && r < off[e + 1]) ex = e;
    tileExpert[i] = ex;
  }
  for (int i = tid; i < CAP; i += 512) { rowTok[i] = -1; rowW[i] = 0.f; }
  __syncthreads();
  for (int t = tid; t < NTOK; t += 512) {
    int ae = assignE[t];
    float2 aw = assignW[t];
    int e0 = ae & 255, e1 = (ae >> 8) & 255;
    int p0 = off[e0] + atomicAdd(&cur[e0], 1);
    rowTok[p0] = t; rowW[p0] = aw.x;
    int p1 = off[e1] + atomicAdd(&cur[e1], 1);
    rowTok[p1] = t; rowW[p1] = aw.y;
    tokRow[t] = make_int2(p0, p1);
  }
}

// =============== GEMM1: 8-phase 256x256 (T3+T4+T5+T2) ===============
// 8 waves (2Mx4N of 128x64), BK=64. LDS 128KB: [slot 2][half 4: A0,A1,B0,B1]
// [128 rows][64 k]. Per K-tile: 4 phases x 16 MFMA; phase q0 also loads the
// wave's 8 B-frags (regs, live across tile). Stage: q0->A0(u+1), q1->A1(u+1),
// q2->B0(u+2), q3->B1(u+2); counted vmcnt(4) once per tile (2 halves in
// flight), vmcnt(0) only at final transition. Raw s_barrier (no drain).
__global__ __launch_bounds__(512, 2) void moe_gemm1_kernel(
    const bf16* __restrict__ A, const bf16* __restrict__ Bt,
    const float* __restrict__ bias, bf16* __restrict__ Hout,
    const int* __restrict__ rowTok, const int* __restrict__ tileExpert) {
  constexpr int N = DH, K = DM, NT = K / 64;  // NT = 16 K-tiles
  __shared__ __align__(16) bf16 lds[2 * 4 * 8192];  // 128 KB
  const int tid = threadIdx.x;
  const int wave = tid >> 6, lane = tid & 63;
  const int wr = wave >> 2, wc = wave & 3;
  const int nbn = N / 256;                 // 16
  const int bid = (int)blockIdx.x;
  const int rt = bid / nbn;
  const int e = tileExpert[rt * 2];        // 256-aligned segments: both 128-subtiles same expert
  if (e < 0) return;
  const int bm0 = rt * 256;
  const int bn0 = (bid % nbn) * 256;
  const bf16* Be = Bt + (size_t)e * N * K;
  const float* be = bias + (size_t)e * N;

  f32x4 acc[8][4];
#pragma unroll
  for (int m = 0; m < 8; m++)
#pragma unroll
    for (int n = 0; n < 4; n++)
#pragma unroll
      for (int j = 0; j < 4; j++) acc[m][n][j] = 0.f;

  // ---- staging geometry: half = 128 rows x 64 k (128B rows, 8 x 16B slots)
  const int srow = tid >> 3;               // 0..63 (row for l=0; +64 for l=1)
  const int csw = ((tid & 7) << 4) ^ ((srow & 7) << 4);  // pre-swizzled source col
  const char* ga[2][2];
  const char* gb[2][2];
#pragma unroll
  for (int h = 0; h < 2; h++)
#pragma unroll
    for (int l = 0; l < 2; l++) {
      int row = h * 128 + srow + l * 64;
      int tok = rowTok[bm0 + row];
      size_t arow = (size_t)(tok < 0 ? 0 : tok);
      ga[h][l] = (const char*)A + arow * (size_t)K * 2 + csw;
      gb[h][l] = (const char*)Be + (size_t)(bn0 + row) * K * 2 + csw;
    }
  char* lw = (char*)lds + wave * 1024;     // wave-uniform LDS base component

  auto STAGE_A = [&](int t, int h) {
    char* d = lw + (t & 1) * 65536 + h * 16384;
    gload16(ga[h][0] + (size_t)t * 128, d);
    gload16(ga[h][1] + (size_t)t * 128, d + 8192);
  };
  auto STAGE_B = [&](int t, int h) {
    char* d = lw + (t & 1) * 65536 + (2 + h) * 16384;
    gload16(gb[h][0] + (size_t)t * 128, d);
    gload16(gb[h][1] + (size_t)t * 128, d + 8192);
  };

  // compute-side LDS half bases (this wave's A-half = wr, B-half = wc>>1)
  const char* lA = (const char*)lds + wr * 16384;
  const char* lB = (const char*)lds + (2 + (wc >> 1)) * 16384;
  const int kbase = (lane >> 4) << 4;      // 16B k-slot within 128B row

  // ---- prologue: tile0 all 4 halves + tile1 B halves; wait tile0 only
  STAGE_A(0, 0); STAGE_A(0, 1); STAGE_B(0, 0); STAGE_B(0, 1);
  STAGE_B(1, 0); STAGE_B(1, 1);
  VM4();
  BAR();

  for (int u = 0; u < NT; ++u) {
    const int s = (u & 1) * 65536;
    bf16x8 bfr[4][2];
#pragma unroll
    for (int q = 0; q < 4; ++q) {
      if (q == 0) {
#pragma unroll
        for (int n = 0; n < 4; n++)
#pragma unroll
          for (int kk = 0; kk < 2; kk++) {
            int r = (wc & 1) * 64 + n * 16 + (lane & 15);
            bfr[n][kk] = *(const bf16x8*)(lB + s + r * 128 +
                              ((kk * 64 + kbase) ^ ((r & 7) << 4)));
          }
      }
      bf16x8 afr[2][2];
#pragma unroll
      for (int i = 0; i < 2; i++)
#pragma unroll
        for (int kk = 0; kk < 2; kk++) {
          int r = (q * 2 + i) * 16 + (lane & 15);
          afr[i][kk] = *(const bf16x8*)(lA + s + r * 128 +
                            ((kk * 64 + kbase) ^ ((r & 7) << 4)));
        }
      if (q == 0 && u + 1 < NT) STAGE_A(u + 1, 0);
      if (q == 1 && u + 1 < NT) STAGE_A(u + 1, 1);
      if (q == 2 && u + 2 < NT) STAGE_B(u + 2, 0);
      if (q == 3 && u + 2 < NT) STAGE_B(u + 2, 1);
      BAR();
      LGKM0();
      __builtin_amdgcn_s_setprio(1);
#pragma unroll
      for (int i = 0; i < 2; i++)
#pragma unroll
        for (int n = 0; n < 4; n++)
#pragma unroll
          for (int kk = 0; kk < 2; kk++)
            acc[q * 2 + i][n] = __builtin_amdgcn_mfma_f32_16x16x32_bf16(
                afr[i][kk], bfr[n][kk], acc[q * 2 + i][n], 0, 0, 0);
      __builtin_amdgcn_s_setprio(0);
      if (q == 3) {
        if (u + 2 < NT) { VM4(); }
        else if (u + 1 < NT) { VM0(); }
      }
      BAR();
    }
  }

  // epilogue: bias + gelu -> Hg
  const int rb = bm0 + wr * 128 + ((lane >> 4) << 2);
  const int cb = bn0 + wc * 64 + (lane & 15);
#pragma unroll
  for (int m = 0; m < 8; m++)
#pragma unroll
    for (int n = 0; n < 4; n++) {
      int c = cb + n * 16;
      float bv = be[c];
#pragma unroll
      for (int j = 0; j < 4; j++) {
        int r = rb + m * 16 + j;
        Hout[(size_t)r * N + c] = (bf16)gelu_f(acc[m][n][j] + bv);
      }
    }
}

// =============== GEMM2: r12/r14-verified 2-phase 128x128 ===============
__global__ __launch_bounds__(256) void moe_gemm2_kernel(
    const bf16* __restrict__ A, const bf16* __restrict__ Bt,
    const float* __restrict__ bias, bf16* __restrict__ Y,
    const float* __restrict__ rowW, const int* __restrict__ tileExpert,
    int N, int K) {
  constexpr int BM = 128, BN = 128, BK = 64;
  __shared__ __align__(16) bf16 As0[BM * BK];
  __shared__ __align__(16) bf16 Bs0[BN * BK];
  __shared__ __align__(16) bf16 As1[BM * BK];
  __shared__ __align__(16) bf16 Bs1[BN * BK];
  const int tid = threadIdx.x;
  const int wave = tid >> 6, lane = tid & 63;
  const int nbn = N / BN;
  const int bid = (int)blockIdx.x;
  int rt = (CAPT - 1) - bid / nbn;         // reverse scan (neutral, kept)
  const int e = tileExpert[rt];
  if (e < 0) return;
  const int bm0 = rt * BM;
  const int bn0 = (bid % nbn) * BN;
  const int wm = (wave >> 1) * 64, wn = (wave & 1) * 64;
  const bf16* Be = Bt + (size_t)e * N * K;
  const float* be = bias + (size_t)e * N;

  f32x4 acc[4][4];
#pragma unroll
  for (int m = 0; m < 4; m++)
#pragma unroll
    for (int n = 0; n < 4; n++)
#pragma unroll
      for (int j = 0; j < 4; j++) acc[m][n][j] = 0.f;

  const int srow = lane >> 3;
  const int scolb = (lane & 7) << 4;

  const char* gaBase[4];
  const char* gbBase[4];
#pragma unroll
  for (int it = 0; it < 4; it++) {
    int chunk = it * 4 + wave;
    int row = chunk * 8 + srow;
    int csw = scolb ^ ((row & 7) << 4);
    gaBase[it] = (const char*)A + (size_t)(bm0 + row) * K * 2 + csw;
    gbBase[it] = (const char*)Be + ((size_t)(bn0 + row)) * K * 2 + csw;
  }

  auto STAGE = [&](int kt, bf16* dstA, bf16* dstB) {
#pragma unroll
    for (int it = 0; it < 4; it++) {
      int chunk = it * 4 + wave;
      gload16(gaBase[it] + (size_t)kt * 2, (char*)dstA + chunk * 1024);
      gload16(gbBase[it] + (size_t)kt * 2, (char*)dstB + chunk * 1024);
    }
  };

  auto COMPUTE = [&](const bf16* sA, const bf16* sB) {
#pragma unroll
    for (int kk = 0; kk < 2; kk++) {
      const int kb = kk * 64 + ((lane >> 4) << 4);
      bf16x8 af[4], bfv[4];
#pragma unroll
      for (int m = 0; m < 4; m++) {
        int r = wm + m * 16 + (lane & 15);
        af[m] = *(const bf16x8*)((const char*)sA + r * 128 + (kb ^ ((r & 7) << 4)));
      }
#pragma unroll
      for (int n = 0; n < 4; n++) {
        int r = wn + n * 16 + (lane & 15);
        bfv[n] = *(const bf16x8*)((const char*)sB + r * 128 + (kb ^ ((r & 7) << 4)));
      }
#pragma unroll
      for (int m = 0; m < 4; m++)
#pragma unroll
        for (int n = 0; n < 4; n++)
          acc[m][n] = __builtin_amdgcn_mfma_f32_16x16x32_bf16(af[m], bfv[n], acc[m][n], 0, 0, 0);
    }
  };

  STAGE(0, As0, Bs0);
  __syncthreads();
  for (int kt = 0; kt < K; kt += 2 * BK) {
    if (kt + BK < K) STAGE(kt + BK, As1, Bs1);
    COMPUTE(As0, Bs0);
    __syncthreads();
    if (kt + 2 * BK < K) STAGE(kt + 2 * BK, As0, Bs0);
    COMPUTE(As1, Bs1);
    __syncthreads();
  }

  const int rb = bm0 + wm + ((lane >> 4) << 2);
  const int cb = bn0 + wn + (lane & 15);
#pragma unroll
  for (int m = 0; m < 4; m++) {
#pragma unroll
    for (int j = 0; j < 4; j++) {
      int r = rb + m * 16 + j;
      float w = rowW[r];
      bf16* yrow = Y + (size_t)r * DM;
#pragma unroll
      for (int n = 0; n < 4; n++) {
        int c = cb + n * 16;
        yrow[c] = (bf16)(w * (acc[m][n][j] + be[c]));
      }
    }
  }
}

// ---------------- combine: out[t] = Y[p0] + Y[p1] ----------------
__global__ void combine_kernel(const bf16* __restrict__ Y,
                               const int2* __restrict__ tokRow,
                               float* __restrict__ out) {
  int wave = threadIdx.x >> 6, lane = threadIdx.x & 63;
  int t = blockIdx.x * 4 + wave;
  int2 pr = tokRow[t];
  const bf16x8* a = (const bf16x8*)(Y + (size_t)pr.x * DM);
  const bf16x8* b = (const bf16x8*)(Y + (size_t)pr.y * DM);
  float4* o = (float4*)(out + (size_t)t * DM);
#pragma unroll
  for (int i = 0; i < 2; i++) {
    int idx = lane + i * 64;
    bf16x8 u = a[idx], v = b[idx];
    float4 s0, s1;
    s0.x = (float)u[0] + (float)v[0]; s0.y = (float)u[1] + (float)v[1];
    s0.z = (float)u[2] + (float)v[2]; s0.w = (float)u[3] + (float)v[3];
    s1.x = (float)u[4] + (float)v[4]; s1.y = (float)u[5] + (float)v[5];
    s1.z = (float)u[6] + (float)v[6]; s1.w = (float)u[7] + (float)v[7];
    o[idx * 2] = s0;
    o[idx * 2 + 1] = s1;
  }
}

extern "C" void kernel_launch(void* const* d_in, const int* in_sizes, int n_in,
                              void* d_out, int out_size, void* d_ws, size_t ws_size,
                              hipStream_t stream) {
  const float* x  = (const float*)d_in[0];
  const float* gw = (const float*)d_in[1];
  const float* gb = (const float*)d_in[2];
  const float* w1 = (const float*)d_in[3];
  const float* b1 = (const float*)d_in[4];
  const float* w2 = (const float*)d_in[5];
  const float* b2 = (const float*)d_in[6];
  float* out = (float*)d_out;

  char* p = (char*)d_ws;
  bf16* xb   = (bf16*)p;  p += (size_t)NTOK * DM * 2;      // 16.8 MB (dead after GEMM1)
  bf16* w1t  = (bf16*)p;  p += (size_t)NE * DM * DH * 2;   // 67 MB   (dead after GEMM1)
  bf16* Hg   = (bf16*)p;  p += (size_t)CAP * DH * 2;       // 151 MB
  bf16* w2t  = (bf16*)p;  p += (size_t)NE * DM * DH * 2;   // 67 MB  [E][D][H]
  int*   assignE = (int*)p;     p += (size_t)NTOK * 4;
  float2* assignW = (float2*)p; p += (size_t)NTOK * 8;
  int*   rowTok = (int*)p;      p += (size_t)CAP * 4;
  float* rowW   = (float*)p;    p += (size_t)CAP * 4;
  int2*  tokRow = (int2*)p;     p += (size_t)NTOK * 8;
  int*   tileExpert = (int*)p;  p += (size_t)CAPT * 4;
  // Y (bf16, 37.7 MB) aliases xb+w1t (83.8 MB; both dead once GEMM2 runs)
  bf16* Y = (bf16*)d_ws;

  transpose_convert2_kernel<<<16384, 256, 0, stream>>>(w1, w1t, w2, w2t);
  gating_kernel<<<NTOK / 4, 256, 0, stream>>>(x, gw, gb, xb, assignE, assignW);
  router_kernel<<<1, 512, 0, stream>>>(assignE, assignW, rowTok, rowW, tokRow, tileExpert);

  // GEMM1 (8-phase 256^2): gathered x @ w1^T -> gelu -> Hg  [CAP x DH]
  moe_gemm1_kernel<<<NTIL * (DH / 256), 512, 0, stream>>>(
      xb, w1t, b1, Hg, rowTok, tileExpert);
  // GEMM2 (2-phase 128^2): Hg @ w2^T -> Y[r] = w*(y+b2)  (bf16, linear)
  moe_gemm2_kernel<<<CAPT * (DM / 128), 256, 0, stream>>>(
      Hg, w2t, b2, Y, rowW, tileExpert, DM, DH);

  combine_kernel<<<NTOK / 4, 256, 0, stream>>>(Y, tokRow, out);
}

// Round 16
// 523.188 us; speedup vs baseline: 1.3004x; 1.0297x over previous
//
#include <hip/hip_runtime.h>
#include <hip/hip_bf16.h>
#include <math.h>

#define NTOK   8192   // B*T = 4*2048
#define DM     1024   // d_model
#define DH     4096   // hidden
#define NE     8      // experts
#define CAP    18432  // max gathered rows: 2*8192 + 8*255, rounded up to 256
#define NTIL   (CAP/256)   // 72 row-tiles of 256
#define CAPT   (CAP/128)   // 144 row-tiles of 128 (tileExpert granularity)

typedef __bf16 bf16;
typedef __bf16 bf16x4 __attribute__((ext_vector_type(4)));
typedef __bf16 bf16x8 __attribute__((ext_vector_type(8)));
typedef float  f32x4  __attribute__((ext_vector_type(4)));

__device__ __forceinline__ void gload16(const void* g, void* l) {
  __builtin_amdgcn_global_load_lds(
      (const __attribute__((address_space(1))) void*)g,
      (__attribute__((address_space(3))) void*)l, 16, 0, 0);
}

#define BAR()   asm volatile("s_barrier" ::: "memory")
#define LGKM0() asm volatile("s_waitcnt lgkmcnt(0)" ::: "memory")
#define VM4()   asm volatile("s_waitcnt vmcnt(4)" ::: "memory")
#define VM0()   asm volatile("s_waitcnt vmcnt(0)" ::: "memory")

// fast GELU (tanh form)
__device__ __forceinline__ float gelu_f(float v) {
  float u = v * v * v;
  float t = 1.5957691216f * v + 0.0713548162726f * u;
  float e = __expf(-t);
  return v * __builtin_amdgcn_rcpf(1.0f + e);
}

// ---- merged fp32 [E][R][C] -> bf16 [E][C][R] transposes (w1 and w2) ----
__global__ void transpose_convert2_kernel(const float* __restrict__ w1,
                                          bf16* __restrict__ w1t,
                                          const float* __restrict__ w2,
                                          bf16* __restrict__ w2t) {
  __shared__ bf16 tile[64][66];
  int id = (int)blockIdx.x;
  const float* src; bf16* dst; int R, C;
  if (id < 8192) { src = w1; dst = w1t; R = DM; C = DH; }
  else           { src = w2; dst = w2t; R = DH; C = DM; id -= 8192; }
  int e = id >> 10;
  int rem = id & 1023;
  int nbx = C >> 6;
  int bx = rem % nbx, by = rem / nbx;
  src += (size_t)e * R * C;
  dst += (size_t)e * R * C;
  int c0 = bx * 64, r0 = by * 64;
  int tid = threadIdx.x;
  int rr = tid >> 4;
  int cc = (tid & 15) * 4;
#pragma unroll
  for (int i = 0; i < 4; i++) {
    int r = rr + i * 16;
    float4 v = *reinterpret_cast<const float4*>(&src[(size_t)(r0 + r) * C + c0 + cc]);
    tile[r][cc + 0] = (bf16)v.x; tile[r][cc + 1] = (bf16)v.y;
    tile[r][cc + 2] = (bf16)v.z; tile[r][cc + 3] = (bf16)v.w;
  }
  __syncthreads();
  int wr = tid >> 3;
  int wm = (tid & 7) * 8;
#pragma unroll
  for (int i = 0; i < 2; i++) {
    int r = wr + i * 32;
    bf16x8 o;
#pragma unroll
    for (int j = 0; j < 8; j++) o[j] = tile[wm + j][r];
    *reinterpret_cast<bf16x8*>(&dst[(size_t)(c0 + r) * R + r0 + wm]) = o;
  }
}

// -- gating fused with x->bf16 convert --
__global__ void gating_kernel(const float* __restrict__ x,
                              const float* __restrict__ gw,
                              const float* __restrict__ gb,
                              bf16* __restrict__ xb,
                              int* __restrict__ assignE,
                              float2* __restrict__ assignW) {
  int wave = threadIdx.x >> 6, lane = threadIdx.x & 63;
  int t = blockIdx.x * 4 + wave;
  const float* xr = x + (size_t)t * DM;
  float4 xv[4];
  const float4* xr4 = reinterpret_cast<const float4*>(xr) + lane * 4;
#pragma unroll
  for (int i = 0; i < 4; i++) xv[i] = xr4[i];
#pragma unroll
  for (int i = 0; i < 2; i++) {
    float4 a = xv[2 * i], b = xv[2 * i + 1];
    bf16x8 o;
    o[0] = (bf16)a.x; o[1] = (bf16)a.y; o[2] = (bf16)a.z; o[3] = (bf16)a.w;
    o[4] = (bf16)b.x; o[5] = (bf16)b.y; o[6] = (bf16)b.z; o[7] = (bf16)b.w;
    reinterpret_cast<bf16x8*>(xb + (size_t)t * DM)[lane * 2 + i] = o;
  }
  float acc[8];
#pragma unroll
  for (int e = 0; e < 8; e++) acc[e] = 0.f;
  int d0 = lane * 16;
#pragma unroll
  for (int j = 0; j < 16; j++) {
    float xvj = reinterpret_cast<const float*>(xv)[j];
    const float4* g = reinterpret_cast<const float4*>(gw + (size_t)(d0 + j) * 8);
    float4 g0 = g[0], g1 = g[1];
    acc[0] += xvj * g0.x; acc[1] += xvj * g0.y; acc[2] += xvj * g0.z; acc[3] += xvj * g0.w;
    acc[4] += xvj * g1.x; acc[5] += xvj * g1.y; acc[6] += xvj * g1.z; acc[7] += xvj * g1.w;
  }
#pragma unroll
  for (int off = 32; off > 0; off >>= 1)
#pragma unroll
    for (int e = 0; e < 8; e++) acc[e] += __shfl_xor(acc[e], off, 64);
  if (lane == 0) {
    float v[8];
#pragma unroll
    for (int e = 0; e < 8; e++) v[e] = acc[e] + gb[e];
    int i0 = 0; float v0 = v[0];
#pragma unroll
    for (int e = 1; e < 8; e++) if (v[e] > v0) { v0 = v[e]; i0 = e; }
    int i1 = -1; float v1 = -1e30f;
#pragma unroll
    for (int e = 0; e < 8; e++) if (e != i0 && v[e] > v1) { v1 = v[e]; i1 = e; }
    float p1 = expf(v1 - v0);
    float den = 1.f + p1;
    assignE[t] = i0 | (i1 << 8);
    assignW[t] = make_float2(1.f / den, p1 / den);
  }
}

// ---- router: 256-aligned segments ----
__global__ void router_kernel(const int* __restrict__ assignE,
                              const float2* __restrict__ assignW,
                              int* __restrict__ rowTok,
                              float* __restrict__ rowW,
                              int2* __restrict__ tokRow,
                              int* __restrict__ tileExpert) {
  __shared__ int cnt[NE], off[NE + 1], cur[NE];
  int tid = threadIdx.x;
  if (tid < NE) cnt[tid] = 0;
  __syncthreads();
  for (int t = tid; t < NTOK; t += 512) {
    int ae = assignE[t];
    atomicAdd(&cnt[ae & 255], 1);
    atomicAdd(&cnt[(ae >> 8) & 255], 1);
  }
  __syncthreads();
  if (tid == 0) {
    int o = 0;
    for (int e = 0; e < NE; e++) { off[e] = o; o += ((cnt[e] + 255) >> 8) << 8; }
    off[NE] = o;
  }
  __syncthreads();
  if (tid < NE) cur[tid] = 0;
  for (int i = tid; i < CAPT; i += 512) {
    int r = i * 128, ex = -1;
#pragma unroll
    for (int e = 0; e < NE; e++)
      if (r >= off[e] && r < off[e + 1]) ex = e;
    tileExpert[i] = ex;
  }
  for (int i = tid; i < CAP; i += 512) { rowTok[i] = -1; rowW[i] = 0.f; }
  __syncthreads();
  for (int t = tid; t < NTOK; t += 512) {
    int ae = assignE[t];
    float2 aw = assignW[t];
    int e0 = ae & 255, e1 = (ae >> 8) & 255;
    int p0 = off[e0] + atomicAdd(&cur[e0], 1);
    rowTok[p0] = t; rowW[p0] = aw.x;
    int p1 = off[e1] + atomicAdd(&cur[e1], 1);
    rowTok[p1] = t; rowW[p1] = aw.y;
    tokRow[t] = make_int2(p0, p1);
  }
}

// =============== 8-phase 256x256 grouped GEMM (r15-verified ledger) ===============
// EPI==0: A gathered via rowTok; Out[r,n] = gelu(C + bias[n])
// EPI==1: A direct;             Out[r,n] = rowW[r] * (C + bias[n])
template <int EPI, int N, int K>
__global__ __launch_bounds__(512, 2) void moe_gemm8_kernel(
    const bf16* __restrict__ A, const bf16* __restrict__ Bt,
    const float* __restrict__ bias, bf16* __restrict__ Out,
    const int* __restrict__ rowTok, const float* __restrict__ rowW,
    const int* __restrict__ tileExpert) {
  constexpr int NT = K / 64;
  __shared__ __align__(16) bf16 lds[2 * 4 * 8192];  // 128 KB
  const int tid = threadIdx.x;
  const int wave = tid >> 6, lane = tid & 63;
  const int wr = wave >> 2, wc = wave & 3;
  const int nbn = N / 256;
  const int bid = (int)blockIdx.x;
  const int rt = bid / nbn;
  const int e = tileExpert[rt * 2];        // 256-aligned segments
  if (e < 0) return;
  const int bm0 = rt * 256;
  const int bn0 = (bid % nbn) * 256;
  const bf16* Be = Bt + (size_t)e * N * K;
  const float* be = bias + (size_t)e * N;

  f32x4 acc[8][4];
#pragma unroll
  for (int m = 0; m < 8; m++)
#pragma unroll
    for (int n = 0; n < 4; n++)
#pragma unroll
      for (int j = 0; j < 4; j++) acc[m][n][j] = 0.f;

  const int srow = tid >> 3;               // 0..63
  const int csw = ((tid & 7) << 4) ^ ((srow & 7) << 4);  // pre-swizzled source
  const char* ga[2][2];
  const char* gb[2][2];
#pragma unroll
  for (int h = 0; h < 2; h++)
#pragma unroll
    for (int l = 0; l < 2; l++) {
      int row = h * 128 + srow + l * 64;
      size_t arow;
      if constexpr (EPI == 0) {
        int tok = rowTok[bm0 + row];
        arow = (size_t)(tok < 0 ? 0 : tok);
      } else {
        arow = (size_t)(bm0 + row);
      }
      ga[h][l] = (const char*)A + arow * (size_t)K * 2 + csw;
      gb[h][l] = (const char*)Be + (size_t)(bn0 + row) * K * 2 + csw;
    }
  char* lw = (char*)lds + wave * 1024;

  auto STAGE_A = [&](int t, int h) {
    char* d = lw + (t & 1) * 65536 + h * 16384;
    gload16(ga[h][0] + (size_t)t * 128, d);
    gload16(ga[h][1] + (size_t)t * 128, d + 8192);
  };
  auto STAGE_B = [&](int t, int h) {
    char* d = lw + (t & 1) * 65536 + (2 + h) * 16384;
    gload16(gb[h][0] + (size_t)t * 128, d);
    gload16(gb[h][1] + (size_t)t * 128, d + 8192);
  };

  const char* lA = (const char*)lds + wr * 16384;
  const char* lB = (const char*)lds + (2 + (wc >> 1)) * 16384;
  const int kbase = (lane >> 4) << 4;

  // prologue: tile0 all 4 halves + tile1 B halves; wait tile0 only
  STAGE_A(0, 0); STAGE_A(0, 1); STAGE_B(0, 0); STAGE_B(0, 1);
  STAGE_B(1, 0); STAGE_B(1, 1);
  VM4();
  BAR();

  for (int u = 0; u < NT; ++u) {
    const int s = (u & 1) * 65536;
    bf16x8 bfr[4][2];
#pragma unroll
    for (int q = 0; q < 4; ++q) {
      if (q == 0) {
#pragma unroll
        for (int n = 0; n < 4; n++)
#pragma unroll
          for (int kk = 0; kk < 2; kk++) {
            int r = (wc & 1) * 64 + n * 16 + (lane & 15);
            bfr[n][kk] = *(const bf16x8*)(lB + s + r * 128 +
                              ((kk * 64 + kbase) ^ ((r & 7) << 4)));
          }
      }
      bf16x8 afr[2][2];
#pragma unroll
      for (int i = 0; i < 2; i++)
#pragma unroll
        for (int kk = 0; kk < 2; kk++) {
          int r = (q * 2 + i) * 16 + (lane & 15);
          afr[i][kk] = *(const bf16x8*)(lA + s + r * 128 +
                            ((kk * 64 + kbase) ^ ((r & 7) << 4)));
        }
      if (q == 0 && u + 1 < NT) STAGE_A(u + 1, 0);
      if (q == 1 && u + 1 < NT) STAGE_A(u + 1, 1);
      if (q == 2 && u + 2 < NT) STAGE_B(u + 2, 0);
      if (q == 3 && u + 2 < NT) STAGE_B(u + 2, 1);
      BAR();
      LGKM0();
      __builtin_amdgcn_s_setprio(1);
#pragma unroll
      for (int i = 0; i < 2; i++)
#pragma unroll
        for (int n = 0; n < 4; n++)
#pragma unroll
          for (int kk = 0; kk < 2; kk++)
            acc[q * 2 + i][n] = __builtin_amdgcn_mfma_f32_16x16x32_bf16(
                afr[i][kk], bfr[n][kk], acc[q * 2 + i][n], 0, 0, 0);
      __builtin_amdgcn_s_setprio(0);
      if (q == 3) {
        if (u + 2 < NT) { VM4(); }
        else if (u + 1 < NT) { VM0(); }
      }
      BAR();
    }
  }

  // epilogue
  const int rb = bm0 + wr * 128 + ((lane >> 4) << 2);
  const int cb = bn0 + wc * 64 + (lane & 15);
  if constexpr (EPI == 0) {
#pragma unroll
    for (int m = 0; m < 8; m++)
#pragma unroll
      for (int n = 0; n < 4; n++) {
        int c = cb + n * 16;
        float bv = be[c];
#pragma unroll
        for (int j = 0; j < 4; j++) {
          int r = rb + m * 16 + j;
          Out[(size_t)r * N + c] = (bf16)gelu_f(acc[m][n][j] + bv);
        }
      }
  } else {
#pragma unroll
    for (int m = 0; m < 8; m++) {
#pragma unroll
      for (int j = 0; j < 4; j++) {
        int r = rb + m * 16 + j;
        float w = rowW[r];
        bf16* yrow = Out + (size_t)r * N;
#pragma unroll
        for (int n = 0; n < 4; n++) {
          int c = cb + n * 16;
          yrow[c] = (bf16)(w * (acc[m][n][j] + be[c]));
        }
      }
    }
  }
}

// ---------------- combine: out[t] = Y[p0] + Y[p1] ----------------
__global__ void combine_kernel(const bf16* __restrict__ Y,
                               const int2* __restrict__ tokRow,
                               float* __restrict__ out) {
  int wave = threadIdx.x >> 6, lane = threadIdx.x & 63;
  int t = blockIdx.x * 4 + wave;
  int2 pr = tokRow[t];
  const bf16x8* a = (const bf16x8*)(Y + (size_t)pr.x * DM);
  const bf16x8* b = (const bf16x8*)(Y + (size_t)pr.y * DM);
  float4* o = (float4*)(out + (size_t)t * DM);
#pragma unroll
  for (int i = 0; i < 2; i++) {
    int idx = lane + i * 64;
    bf16x8 u = a[idx], v = b[idx];
    float4 s0, s1;
    s0.x = (float)u[0] + (float)v[0]; s0.y = (float)u[1] + (float)v[1];
    s0.z = (float)u[2] + (float)v[2]; s0.w = (float)u[3] + (float)v[3];
    s1.x = (float)u[4] + (float)v[4]; s1.y = (float)u[5] + (float)v[5];
    s1.z = (float)u[6] + (float)v[6]; s1.w = (float)u[7] + (float)v[7];
    o[idx * 2] = s0;
    o[idx * 2 + 1] = s1;
  }
}

extern "C" void kernel_launch(void* const* d_in, const int* in_sizes, int n_in,
                              void* d_out, int out_size, void* d_ws, size_t ws_size,
                              hipStream_t stream) {
  const float* x  = (const float*)d_in[0];
  const float* gw = (const float*)d_in[1];
  const float* gb = (const float*)d_in[2];
  const float* w1 = (const float*)d_in[3];
  const float* b1 = (const float*)d_in[4];
  const float* w2 = (const float*)d_in[5];
  const float* b2 = (const float*)d_in[6];
  float* out = (float*)d_out;

  char* p = (char*)d_ws;
  bf16* xb   = (bf16*)p;  p += (size_t)NTOK * DM * 2;      // 16.8 MB (dead after GEMM1)
  bf16* w1t  = (bf16*)p;  p += (size_t)NE * DM * DH * 2;   // 67 MB   (dead after GEMM1)
  bf16* Hg   = (bf16*)p;  p += (size_t)CAP * DH * 2;       // 151 MB
  bf16* w2t  = (bf16*)p;  p += (size_t)NE * DM * DH * 2;   // 67 MB  [E][D][H]
  int*   assignE = (int*)p;     p += (size_t)NTOK * 4;
  float2* assignW = (float2*)p; p += (size_t)NTOK * 8;
  int*   rowTok = (int*)p;      p += (size_t)CAP * 4;
  float* rowW   = (float*)p;    p += (size_t)CAP * 4;
  int2*  tokRow = (int2*)p;     p += (size_t)NTOK * 8;
  int*   tileExpert = (int*)p;  p += (size_t)CAPT * 4;
  // Y (bf16, 37.7 MB) aliases xb+w1t (83.8 MB; both dead once GEMM2 runs)
  bf16* Y = (bf16*)d_ws;

  transpose_convert2_kernel<<<16384, 256, 0, stream>>>(w1, w1t, w2, w2t);
  gating_kernel<<<NTOK / 4, 256, 0, stream>>>(x, gw, gb, xb, assignE, assignW);
  router_kernel<<<1, 512, 0, stream>>>(assignE, assignW, rowTok, rowW, tokRow, tileExpert);

  // GEMM1 (8-phase 256^2): gathered x @ w1^T -> gelu -> Hg  [CAP x DH]
  moe_gemm8_kernel<0, DH, DM><<<NTIL * (DH / 256), 512, 0, stream>>>(
      xb, w1t, b1, Hg, rowTok, nullptr, tileExpert);
  // GEMM2 (8-phase 256^2): Hg @ w2^T -> Y[r] = w*(y+b2)  (bf16, linear)
  moe_gemm8_kernel<1, DM, DH><<<NTIL * (DM / 256), 512, 0, stream>>>(
      Hg, w2t, b2, Y, nullptr, rowW, tileExpert);

  combine_kernel<<<NTOK / 4, 256, 0, stream>>>(Y, tokRow, out);
}

// Round 17
// 512.449 us; speedup vs baseline: 1.3276x; 1.0210x over previous
//
#include <hip/hip_runtime.h>
#include <hip/hip_bf16.h>
#include <math.h>

#define NTOK   8192   // B*T = 4*2048
#define DM     1024   // d_model
#define DH     4096   // hidden
#define NE     8      // experts
#define CAP    18432  // max gathered rows: 2*8192 + 8*255, rounded up to 256
#define NTIL   (CAP/256)   // 72 row-tiles of 256
#define CAPT   (CAP/128)   // 144 row-tiles of 128 (tileExpert granularity)

typedef __bf16 bf16;
typedef __bf16 bf16x4 __attribute__((ext_vector_type(4)));
typedef __bf16 bf16x8 __attribute__((ext_vector_type(8)));
typedef float  f32x4  __attribute__((ext_vector_type(4)));

__device__ __forceinline__ void gload16(const void* g, void* l) {
  __builtin_amdgcn_global_load_lds(
      (const __attribute__((address_space(1))) void*)g,
      (__attribute__((address_space(3))) void*)l, 16, 0, 0);
}

#define BAR()   asm volatile("s_barrier" ::: "memory")
#define LGKM0() asm volatile("s_waitcnt lgkmcnt(0)" ::: "memory")
#define VM4()   asm volatile("s_waitcnt vmcnt(4)" ::: "memory")
#define VM0()   asm volatile("s_waitcnt vmcnt(0)" ::: "memory")

// fast GELU (tanh form)
__device__ __forceinline__ float gelu_f(float v) {
  float u = v * v * v;
  float t = 1.5957691216f * v + 0.0713548162726f * u;
  float e = __expf(-t);
  return v * __builtin_amdgcn_rcpf(1.0f + e);
}

// ---- merged fp32 [E][R][C] -> bf16 [E][C][R] transposes (w1 and w2) ----
__global__ void transpose_convert2_kernel(const float* __restrict__ w1,
                                          bf16* __restrict__ w1t,
                                          const float* __restrict__ w2,
                                          bf16* __restrict__ w2t) {
  __shared__ bf16 tile[64][66];
  int id = (int)blockIdx.x;
  const float* src; bf16* dst; int R, C;
  if (id < 8192) { src = w1; dst = w1t; R = DM; C = DH; }
  else           { src = w2; dst = w2t; R = DH; C = DM; id -= 8192; }
  int e = id >> 10;
  int rem = id & 1023;
  int nbx = C >> 6;
  int bx = rem % nbx, by = rem / nbx;
  src += (size_t)e * R * C;
  dst += (size_t)e * R * C;
  int c0 = bx * 64, r0 = by * 64;
  int tid = threadIdx.x;
  int rr = tid >> 4;
  int cc = (tid & 15) * 4;
#pragma unroll
  for (int i = 0; i < 4; i++) {
    int r = rr + i * 16;
    float4 v = *reinterpret_cast<const float4*>(&src[(size_t)(r0 + r) * C + c0 + cc]);
    tile[r][cc + 0] = (bf16)v.x; tile[r][cc + 1] = (bf16)v.y;
    tile[r][cc + 2] = (bf16)v.z; tile[r][cc + 3] = (bf16)v.w;
  }
  __syncthreads();
  int wr = tid >> 3;
  int wm = (tid & 7) * 8;
#pragma unroll
  for (int i = 0; i < 2; i++) {
    int r = wr + i * 32;
    bf16x8 o;
#pragma unroll
    for (int j = 0; j < 8; j++) o[j] = tile[wm + j][r];
    *reinterpret_cast<bf16x8*>(&dst[(size_t)(c0 + r) * R + r0 + wm]) = o;
  }
}

// -- gating fused with x->bf16 convert --
__global__ void gating_kernel(const float* __restrict__ x,
                              const float* __restrict__ gw,
                              const float* __restrict__ gb,
                              bf16* __restrict__ xb,
                              int* __restrict__ assignE,
                              float2* __restrict__ assignW) {
  int wave = threadIdx.x >> 6, lane = threadIdx.x & 63;
  int t = blockIdx.x * 4 + wave;
  const float* xr = x + (size_t)t * DM;
  float4 xv[4];
  const float4* xr4 = reinterpret_cast<const float4*>(xr) + lane * 4;
#pragma unroll
  for (int i = 0; i < 4; i++) xv[i] = xr4[i];
#pragma unroll
  for (int i = 0; i < 2; i++) {
    float4 a = xv[2 * i], b = xv[2 * i + 1];
    bf16x8 o;
    o[0] = (bf16)a.x; o[1] = (bf16)a.y; o[2] = (bf16)a.z; o[3] = (bf16)a.w;
    o[4] = (bf16)b.x; o[5] = (bf16)b.y; o[6] = (bf16)b.z; o[7] = (bf16)b.w;
    reinterpret_cast<bf16x8*>(xb + (size_t)t * DM)[lane * 2 + i] = o;
  }
  float acc[8];
#pragma unroll
  for (int e = 0; e < 8; e++) acc[e] = 0.f;
  int d0 = lane * 16;
#pragma unroll
  for (int j = 0; j < 16; j++) {
    float xvj = reinterpret_cast<const float*>(xv)[j];
    const float4* g = reinterpret_cast<const float4*>(gw + (size_t)(d0 + j) * 8);
    float4 g0 = g[0], g1 = g[1];
    acc[0] += xvj * g0.x; acc[1] += xvj * g0.y; acc[2] += xvj * g0.z; acc[3] += xvj * g0.w;
    acc[4] += xvj * g1.x; acc[5] += xvj * g1.y; acc[6] += xvj * g1.z; acc[7] += xvj * g1.w;
  }
#pragma unroll
  for (int off = 32; off > 0; off >>= 1)
#pragma unroll
    for (int e = 0; e < 8; e++) acc[e] += __shfl_xor(acc[e], off, 64);
  if (lane == 0) {
    float v[8];
#pragma unroll
    for (int e = 0; e < 8; e++) v[e] = acc[e] + gb[e];
    int i0 = 0; float v0 = v[0];
#pragma unroll
    for (int e = 1; e < 8; e++) if (v[e] > v0) { v0 = v[e]; i0 = e; }
    int i1 = -1; float v1 = -1e30f;
#pragma unroll
    for (int e = 0; e < 8; e++) if (e != i0 && v[e] > v1) { v1 = v[e]; i1 = e; }
    float p1 = expf(v1 - v0);
    float den = 1.f + p1;
    assignE[t] = i0 | (i1 << 8);
    assignW[t] = make_float2(1.f / den, p1 / den);
  }
}

// ---- router: 256-aligned segments ----
__global__ void router_kernel(const int* __restrict__ assignE,
                              const float2* __restrict__ assignW,
                              int* __restrict__ rowTok,
                              float* __restrict__ rowW,
                              int2* __restrict__ tokRow,
                              int* __restrict__ tileExpert) {
  __shared__ int cnt[NE], off[NE + 1], cur[NE];
  int tid = threadIdx.x;
  if (tid < NE) cnt[tid] = 0;
  __syncthreads();
  for (int t = tid; t < NTOK; t += 512) {
    int ae = assignE[t];
    atomicAdd(&cnt[ae & 255], 1);
    atomicAdd(&cnt[(ae >> 8) & 255], 1);
  }
  __syncthreads();
  if (tid == 0) {
    int o = 0;
    for (int e = 0; e < NE; e++) { off[e] = o; o += ((cnt[e] + 255) >> 8) << 8; }
    off[NE] = o;
  }
  __syncthreads();
  if (tid < NE) cur[tid] = 0;
  for (int i = tid; i < CAPT; i += 512) {
    int r = i * 128, ex = -1;
#pragma unroll
    for (int e = 0; e < NE; e++)
      if (r >= off[e] && r < off[e + 1]) ex = e;
    tileExpert[i] = ex;
  }
  for (int i = tid; i < CAP; i += 512) { rowTok[i] = -1; rowW[i] = 0.f; }
  __syncthreads();
  for (int t = tid; t < NTOK; t += 512) {
    int ae = assignE[t];
    float2 aw = assignW[t];
    int e0 = ae & 255, e1 = (ae >> 8) & 255;
    int p0 = off[e0] + atomicAdd(&cur[e0], 1);
    rowTok[p0] = t; rowW[p0] = aw.x;
    int p1 = off[e1] + atomicAdd(&cur[e1], 1);
    rowTok[p1] = t; rowW[p1] = aw.y;
    tokRow[t] = make_int2(p0, p1);
  }
}

// =============== 8-phase 256x256 grouped GEMM (r15/r16-verified ledger) ===============
// K = extent of this block's K-slice; LDA/LDB = row strides (elements).
// NSPLIT: split-K factor; slice ks = bid % NSPLIT, A/B advanced ks*K columns,
// output written to slice ks (Out + ks*CAP*N). Combine sums slices.
// EPI==0: A gathered via rowTok; Out[r,n] = gelu(C + bias[n])
// EPI==1: A direct;             Out[r,n] = rowW[r] * (C + bias[n])  (bias only in slice 0? no: bias added per slice 0 only)
// NOTE: bias must be added exactly once -> only slice 0 adds it.
template <int EPI, int N, int K, int LDA, int LDB, int NSPLIT>
__global__ __launch_bounds__(512, 2) void moe_gemm8_kernel(
    const bf16* __restrict__ A, const bf16* __restrict__ Bt,
    const float* __restrict__ bias, bf16* __restrict__ Out,
    const int* __restrict__ rowTok, const float* __restrict__ rowW,
    const int* __restrict__ tileExpert) {
  constexpr int NT = K / 64;
  __shared__ __align__(16) bf16 lds[2 * 4 * 8192];  // 128 KB
  const int tid = threadIdx.x;
  const int wave = tid >> 6, lane = tid & 63;
  const int wr = wave >> 2, wc = wave & 3;
  const int nbn = N / 256;
  const int bid = (int)blockIdx.x;
  const int ks = bid % NSPLIT;
  const int bb = bid / NSPLIT;
  const int rt = bb / nbn;
  const int e = tileExpert[rt * 2];        // 256-aligned segments
  if (e < 0) return;
  const int bm0 = rt * 256;
  const int bn0 = (bb % nbn) * 256;
  const bf16* Ae = A + (size_t)ks * K;     // column offset into A rows
  const bf16* Be = Bt + (size_t)e * N * LDB + (size_t)ks * K;
  const float* be = bias + (size_t)e * N;

  f32x4 acc[8][4];
#pragma unroll
  for (int m = 0; m < 8; m++)
#pragma unroll
    for (int n = 0; n < 4; n++)
#pragma unroll
      for (int j = 0; j < 4; j++) acc[m][n][j] = 0.f;

  const int srow = tid >> 3;               // 0..63
  const int csw = ((tid & 7) << 4) ^ ((srow & 7) << 4);  // pre-swizzled source
  const char* ga[2][2];
  const char* gb[2][2];
#pragma unroll
  for (int h = 0; h < 2; h++)
#pragma unroll
    for (int l = 0; l < 2; l++) {
      int row = h * 128 + srow + l * 64;
      size_t arow;
      if constexpr (EPI == 0) {
        int tok = rowTok[bm0 + row];
        arow = (size_t)(tok < 0 ? 0 : tok);
      } else {
        arow = (size_t)(bm0 + row);
      }
      ga[h][l] = (const char*)Ae + arow * (size_t)LDA * 2 + csw;
      gb[h][l] = (const char*)Be + (size_t)(bn0 + row) * LDB * 2 + csw;
    }
  char* lw = (char*)lds + wave * 1024;

  auto STAGE_A = [&](int t, int h) {
    char* d = lw + (t & 1) * 65536 + h * 16384;
    gload16(ga[h][0] + (size_t)t * 128, d);
    gload16(ga[h][1] + (size_t)t * 128, d + 8192);
  };
  auto STAGE_B = [&](int t, int h) {
    char* d = lw + (t & 1) * 65536 + (2 + h) * 16384;
    gload16(gb[h][0] + (size_t)t * 128, d);
    gload16(gb[h][1] + (size_t)t * 128, d + 8192);
  };

  const char* lA = (const char*)lds + wr * 16384;
  const char* lB = (const char*)lds + (2 + (wc >> 1)) * 16384;
  const int kbase = (lane >> 4) << 4;

  // prologue: tile0 all 4 halves + tile1 B halves; wait tile0 only
  STAGE_A(0, 0); STAGE_A(0, 1); STAGE_B(0, 0); STAGE_B(0, 1);
  STAGE_B(1, 0); STAGE_B(1, 1);
  VM4();
  BAR();

  for (int u = 0; u < NT; ++u) {
    const int s = (u & 1) * 65536;
    bf16x8 bfr[4][2];
#pragma unroll
    for (int q = 0; q < 4; ++q) {
      if (q == 0) {
#pragma unroll
        for (int n = 0; n < 4; n++)
#pragma unroll
          for (int kk = 0; kk < 2; kk++) {
            int r = (wc & 1) * 64 + n * 16 + (lane & 15);
            bfr[n][kk] = *(const bf16x8*)(lB + s + r * 128 +
                              ((kk * 64 + kbase) ^ ((r & 7) << 4)));
          }
      }
      bf16x8 afr[2][2];
#pragma unroll
      for (int i = 0; i < 2; i++)
#pragma unroll
        for (int kk = 0; kk < 2; kk++) {
          int r = (q * 2 + i) * 16 + (lane & 15);
          afr[i][kk] = *(const bf16x8*)(lA + s + r * 128 +
                            ((kk * 64 + kbase) ^ ((r & 7) << 4)));
        }
      if (q == 0 && u + 1 < NT) STAGE_A(u + 1, 0);
      if (q == 1 && u + 1 < NT) STAGE_A(u + 1, 1);
      if (q == 2 && u + 2 < NT) STAGE_B(u + 2, 0);
      if (q == 3 && u + 2 < NT) STAGE_B(u + 2, 1);
      BAR();
      LGKM0();
      __builtin_amdgcn_s_setprio(1);
#pragma unroll
      for (int i = 0; i < 2; i++)
#pragma unroll
        for (int n = 0; n < 4; n++)
#pragma unroll
          for (int kk = 0; kk < 2; kk++)
            acc[q * 2 + i][n] = __builtin_amdgcn_mfma_f32_16x16x32_bf16(
                afr[i][kk], bfr[n][kk], acc[q * 2 + i][n], 0, 0, 0);
      __builtin_amdgcn_s_setprio(0);
      if (q == 3) {
        if (u + 2 < NT) { VM4(); }
        else if (u + 1 < NT) { VM0(); }
      }
      BAR();
    }
  }

  // epilogue
  const int rb = bm0 + wr * 128 + ((lane >> 4) << 2);
  const int cb = bn0 + wc * 64 + (lane & 15);
  if constexpr (EPI == 0) {
#pragma unroll
    for (int m = 0; m < 8; m++)
#pragma unroll
      for (int n = 0; n < 4; n++) {
        int c = cb + n * 16;
        float bv = be[c];
#pragma unroll
        for (int j = 0; j < 4; j++) {
          int r = rb + m * 16 + j;
          Out[(size_t)r * N + c] = (bf16)gelu_f(acc[m][n][j] + bv);
        }
      }
  } else {
    bf16* Os = Out + (size_t)ks * CAP * N;   // per-slice output
#pragma unroll
    for (int m = 0; m < 8; m++) {
#pragma unroll
      for (int j = 0; j < 4; j++) {
        int r = rb + m * 16 + j;
        float w = rowW[r];
        bf16* yrow = Os + (size_t)r * N;
#pragma unroll
        for (int n = 0; n < 4; n++) {
          int c = cb + n * 16;
          float bv = (ks == 0) ? be[c] : 0.f;   // bias exactly once
          yrow[c] = (bf16)(w * (acc[m][n][j] + bv));
        }
      }
    }
  }
}

// ------- combine: out[t] = sum over slices and slots of Y[ks][p] -------
__global__ void combine_kernel(const bf16* __restrict__ Y,
                               const int2* __restrict__ tokRow,
                               float* __restrict__ out) {
  int wave = threadIdx.x >> 6, lane = threadIdx.x & 63;
  int t = blockIdx.x * 4 + wave;
  int2 pr = tokRow[t];
  const bf16x8* a0 = (const bf16x8*)(Y + (size_t)pr.x * DM);
  const bf16x8* b0 = (const bf16x8*)(Y + (size_t)pr.y * DM);
  const bf16x8* a1 = (const bf16x8*)(Y + (size_t)CAP * DM + (size_t)pr.x * DM);
  const bf16x8* b1 = (const bf16x8*)(Y + (size_t)CAP * DM + (size_t)pr.y * DM);
  float4* o = (float4*)(out + (size_t)t * DM);
#pragma unroll
  for (int i = 0; i < 2; i++) {
    int idx = lane + i * 64;
    bf16x8 u = a0[idx], v = b0[idx], p = a1[idx], q = b1[idx];
    float4 s0, s1;
    s0.x = (float)u[0] + (float)v[0] + (float)p[0] + (float)q[0];
    s0.y = (float)u[1] + (float)v[1] + (float)p[1] + (float)q[1];
    s0.z = (float)u[2] + (float)v[2] + (float)p[2] + (float)q[2];
    s0.w = (float)u[3] + (float)v[3] + (float)p[3] + (float)q[3];
    s1.x = (float)u[4] + (float)v[4] + (float)p[4] + (float)q[4];
    s1.y = (float)u[5] + (float)v[5] + (float)p[5] + (float)q[5];
    s1.z = (float)u[6] + (float)v[6] + (float)p[6] + (float)q[6];
    s1.w = (float)u[7] + (float)v[7] + (float)p[7] + (float)q[7];
    o[idx * 2] = s0;
    o[idx * 2 + 1] = s1;
  }
}

extern "C" void kernel_launch(void* const* d_in, const int* in_sizes, int n_in,
                              void* d_out, int out_size, void* d_ws, size_t ws_size,
                              hipStream_t stream) {
  const float* x  = (const float*)d_in[0];
  const float* gw = (const float*)d_in[1];
  const float* gb = (const float*)d_in[2];
  const float* w1 = (const float*)d_in[3];
  const float* b1 = (const float*)d_in[4];
  const float* w2 = (const float*)d_in[5];
  const float* b2 = (const float*)d_in[6];
  float* out = (float*)d_out;

  char* p = (char*)d_ws;
  bf16* xb   = (bf16*)p;  p += (size_t)NTOK * DM * 2;      // 16.8 MB (dead after GEMM1)
  bf16* w1t  = (bf16*)p;  p += (size_t)NE * DM * DH * 2;   // 67 MB   (dead after GEMM1)
  bf16* Hg   = (bf16*)p;  p += (size_t)CAP * DH * 2;       // 151 MB
  bf16* w2t  = (bf16*)p;  p += (size_t)NE * DM * DH * 2;   // 67 MB  [E][D][H]
  int*   assignE = (int*)p;     p += (size_t)NTOK * 4;
  float2* assignW = (float2*)p; p += (size_t)NTOK * 8;
  int*   rowTok = (int*)p;      p += (size_t)CAP * 4;
  float* rowW   = (float*)p;    p += (size_t)CAP * 4;
  int2*  tokRow = (int2*)p;     p += (size_t)NTOK * 8;
  int*   tileExpert = (int*)p;  p += (size_t)CAPT * 4;
  // Y: 2 split-K slices, bf16 [2][CAP][DM] = 75.5 MB, aliases xb+w1t (83.9 MB)
  bf16* Y = (bf16*)d_ws;

  transpose_convert2_kernel<<<16384, 256, 0, stream>>>(w1, w1t, w2, w2t);
  gating_kernel<<<NTOK / 4, 256, 0, stream>>>(x, gw, gb, xb, assignE, assignW);
  router_kernel<<<1, 512, 0, stream>>>(assignE, assignW, rowTok, rowW, tokRow, tileExpert);

  // GEMM1 (8-phase 256^2, no split): gathered x @ w1^T -> gelu -> Hg
  moe_gemm8_kernel<0, DH, DM, DM, DM, 1><<<NTIL * (DH / 256), 512, 0, stream>>>(
      xb, w1t, b1, Hg, rowTok, nullptr, tileExpert);
  // GEMM2 (8-phase 256^2, split-K=2 -> 576 blocks, kills 288-block tail):
  //   Y[ks][r] = w * (partial_acc + (ks==0 ? b2 : 0))
  moe_gemm8_kernel<1, DM, DH / 2, DH, DH, 2><<<NTIL * (DM / 256) * 2, 512, 0, stream>>>(
      Hg, w2t, b2, Y, nullptr, rowW, tileExpert);

  combine_kernel<<<NTOK / 4, 256, 0, stream>>>(Y, tokRow, out);
}